// Round 6
// baseline (1512.399 us; speedup 1.0000x reference)
//
#include <hip/hip_runtime.h>
#include <hip/hip_fp16.h>
#include <hip/hip_bf16.h>
#include <cstdint>

#define TLEN  256
#define HD    128
#define BATCH 8
#define VOCAB 32000
#define EMBD  32

typedef __attribute__((ext_vector_type(8))) short short8v;
typedef __attribute__((ext_vector_type(8))) unsigned short ushort8v;
typedef __attribute__((ext_vector_type(4))) float f32x4;

__device__ __forceinline__ float tanhfast(float x){
  float e = __builtin_amdgcn_exp2f(x * 2.8853900817779268f);
  return 1.0f - 2.0f * __builtin_amdgcn_rcpf(e + 1.0f);
}
__device__ __forceinline__ unsigned short f2bf(float f){
  unsigned u = __float_as_uint(f);
  return (unsigned short)((u + 0x7fffu + ((u >> 16) & 1u)) >> 16);
}
__device__ __forceinline__ float h2f(unsigned short u){
  return __half2float(__ushort_as_half(u));
}
__device__ __forceinline__ unsigned short f2h(float f){
  return __half_as_ushort(__float2half(f));
}
__device__ __forceinline__ void gload_lds16(const void* g, void* l){
  __builtin_amdgcn_global_load_lds((const __attribute__((address_space(1))) void*)g,
                                   (__attribute__((address_space(3))) void*)l, 16, 0, 0);
}

// ---------------- prep 1: ex[b,t,c] = emb[x[b,t]] @ W_ih[0:32] + b_ih + b_hh ----------------
__global__ void prep_ex_kernel(const int* __restrict__ x, const float* __restrict__ emb,
                               const float* __restrict__ W_ih, const float* __restrict__ b_ih,
                               const float* __restrict__ b_hh, float* __restrict__ ex){
  int bt = blockIdx.x;
  int c  = threadIdx.x;
  int ix = x[bt];
  const float* er = emb + (long)ix * EMBD;
  float acc = b_ih[c] + b_hh[c];
  #pragma unroll
  for (int e = 0; e < EMBD; ++e) acc += er[e] * W_ih[e * HD + c];
  ex[bt * HD + c] = acc;
}

// ---------------- prep 2: Wbt[n][k] = bf16(W_out[k][n]) ----------------
__global__ void prep_wt_kernel(const float* __restrict__ W_out, unsigned short* __restrict__ Wbt){
  __shared__ float tile[32][33];
  int tx = threadIdx.x & 31, ty = threadIdx.x >> 5;
  int n0 = blockIdx.x * 32, k0 = blockIdx.y * 32;
  #pragma unroll
  for (int j = 0; j < 4; ++j){
    int k = ty + j * 8;
    tile[k][tx] = W_out[(long)(k0 + k) * VOCAB + n0 + tx];
  }
  __syncthreads();
  #pragma unroll
  for (int j = 0; j < 4; ++j){
    int n = ty + j * 8;
    Wbt[(long)(n0 + n) * HD + k0 + tx] = f2bf(tile[tx][n]);
  }
}

// ---------------- scan: one workgroup per batch element ----------------
// keysB holds F = e^k (fp16); hidB holds h (fp16). Both rows swizzled by
// chunk ^ ((s ^ (s>>4)) & 7)  (both-sides rule: writer and reader use same XOR).
__launch_bounds__(1024)
__global__ void scan_kernel(const float* __restrict__ W_attn, const float* __restrict__ U_attn,
                            const float* __restrict__ v_attn, const float* __restrict__ W_ih,
                            const float* __restrict__ W_hh, const float* __restrict__ ex,
                            unsigned short* __restrict__ out_bf, float* __restrict__ h_final){
  extern __shared__ char lds[];
  char* keysB = lds;                   // 64 KB fp16 (F = e^k)
  char* hidB  = lds + 65536;           // 64 KB fp16 (h history)
  float* fbuf   = (float*)(lds + 131072);
  float* E_pad    = fbuf;              // 160 (80B-stride pad): e^{2q}
  float* h_pad    = fbuf + 160;        // 160
  float* ctx_pad  = fbuf + 320;        // 160
  float* hh_lds   = fbuf + 480;        // 128
  float* scores_e = fbuf + 608;        // 256
  float* pp       = fbuf + 864;        // 16
  float* v_pad    = fbuf + 880;        // 160

  const int b    = blockIdx.x;
  const int tid  = threadIdx.x;
  const int lane = tid & 63, wv = tid >> 6;
  const int c_   = tid >> 3, rg = tid & 7;      // phase 1/4 mapping
  const int sg   = lane >> 3, cg = lane & 7;    // phase 2/3 mapping

  const float LOG2E = 1.4426950408889634f;
  const float C2F   = 2.8853900817779268f;

  // ---- init small buffers ----
  if (tid < HD){ hh_lds[tid] = 0.f; v_pad[tid + (tid>>4)*4] = v_attn[tid]; }
  if (tid < 160) ctx_pad[tid] = 0.f;

  // ---- stage weights into VGPRs (f32) ----
  float Wa[16], Ua[16], Wh[16], Wc[16];
  {
    float* stage = (float*)lds;        // reuse keysB area
    float4* d4 = (float4*)stage;
    {
      const float4* s4 = (const float4*)W_attn;
      for (int i = 0; i < 4; ++i) d4[tid + i*1024] = s4[tid + i*1024];
      __syncthreads();
      #pragma unroll
      for (int i = 0; i < 16; ++i) Wa[i] = stage[(rg*16 + i)*HD + c_];
      __syncthreads();
    }
    {
      const float4* s4 = (const float4*)U_attn;
      for (int i = 0; i < 4; ++i) d4[tid + i*1024] = s4[tid + i*1024];
      __syncthreads();
      #pragma unroll
      for (int i = 0; i < 16; ++i) Ua[i] = stage[(rg*16 + i)*HD + c_];
      __syncthreads();
    }
    {
      const float4* s4 = (const float4*)W_hh;
      for (int i = 0; i < 4; ++i) d4[tid + i*1024] = s4[tid + i*1024];
      __syncthreads();
      #pragma unroll
      for (int i = 0; i < 16; ++i) Wh[i] = stage[(rg*16 + i)*HD + c_];
      __syncthreads();
    }
    {
      const float4* s4 = (const float4*)(W_ih + EMBD*HD);
      for (int i = 0; i < 4; ++i) d4[tid + i*1024] = s4[tid + i*1024];
      __syncthreads();
      #pragma unroll
      for (int i = 0; i < 16; ++i) Wc[i] = stage[(rg*16 + i)*HD + c_];
      __syncthreads();
    }
  }

  // ---- zero ALL of keysB (64 KB = 4096 float4s): unwritten rows must read
  //      as F=0 -> D=1. (Round-5 bug: only 32 KB was zeroed; stale staging
  //      bytes reinterpreted as fp16 NaN/Inf poisoned paired-rcp scores.)
  {
    float4 z4 = {0.f, 0.f, 0.f, 0.f};
    ((float4*)keysB)[tid]        = z4;
    ((float4*)keysB)[tid + 1024] = z4;
    ((float4*)keysB)[tid + 2048] = z4;
    ((float4*)keysB)[tid + 3072] = z4;
  }
  __syncthreads();

  // ---- v in registers (cols cg*16..+15) + its sum ----
  float vreg[16], Vsum = 0.f;
  {
    const float4* v4 = (const float4*)(v_pad + cg*20);
    #pragma unroll
    for (int i = 0; i < 4; ++i){
      float4 vv = v4[i];
      vreg[i*4+0]=vv.x; vreg[i*4+1]=vv.y; vreg[i*4+2]=vv.z; vreg[i*4+3]=vv.w;
    }
    #pragma unroll
    for (int j = 0; j < 16; ++j) Vsum += vreg[j];
  }

  const float* exb = ex + (long)b * TLEN * HD;

  for (int t = 0; t < TLEN; ++t){
    float exv = exb[t * HD + c_];

    if (t > 0){
      // ---- phase 1: q,k,hh GEMVs (f32); write E=e^{2q}, F=e^k, hh ----
      {
        float aq = 0.f, ak = 0.f, ah = 0.f;
        const float4* h4 = (const float4*)(h_pad + rg*20);
        #pragma unroll
        for (int i4 = 0; i4 < 4; ++i4){
          float4 hv = h4[i4];
          aq += hv.x*Wa[i4*4+0] + hv.y*Wa[i4*4+1] + hv.z*Wa[i4*4+2] + hv.w*Wa[i4*4+3];
          ak += hv.x*Ua[i4*4+0] + hv.y*Ua[i4*4+1] + hv.z*Ua[i4*4+2] + hv.w*Ua[i4*4+3];
          ah += hv.x*Wh[i4*4+0] + hv.y*Wh[i4*4+1] + hv.z*Wh[i4*4+2] + hv.w*Wh[i4*4+3];
        }
        #pragma unroll
        for (int m = 1; m < 8; m <<= 1){
          aq += __shfl_xor(aq, m); ak += __shfl_xor(ak, m); ah += __shfl_xor(ah, m);
        }
        if (rg == 0){
          E_pad[c_ + (c_>>4)*4] = __builtin_amdgcn_exp2f(aq * C2F);     // e^{2q}
          hh_lds[c_] = ah;
          int s = t - 1;
          float F = fminf(__builtin_amdgcn_exp2f(ak * LOG2E), 60000.f); // e^k, clamped
          *(unsigned short*)(keysB + s*256 +
              (((c_>>4) ^ ((s ^ (s>>4)) & 7)) << 5) + ((c_&15)<<1)) = f2h(F);
        }
      }
      __syncthreads();  // S1

      // ---- phase 2: e_s = exp(v . tanh(q+k_s)); tanh = 1 - 2/(1+E*F^2) ----
      // s-striping: wave wv owns s == wv (mod 16); paired rcp across (sa, sb=sa+128)
      {
        float Ereg[16];
        {
          const float4* E4 = (const float4*)(E_pad + cg*20);
          #pragma unroll
          for (int i = 0; i < 4; ++i){
            float4 ev = E4[i];
            Ereg[i*4+0]=ev.x; Ereg[i*4+1]=ev.y; Ereg[i*4+2]=ev.z; Ereg[i*4+3]=ev.w;
          }
        }
        const int sa = 16*sg + wv, sb = sa + 128;
        const char* kba = keysB + sa*256 + (((cg ^ wv ^ sg) & 7) << 5);
        ushort8v ka0 = *(const ushort8v*)kba;
        ushort8v ka1 = *(const ushort8v*)(kba + 16);
        ushort8v kb0 = *(const ushort8v*)(kba + 32768);
        ushort8v kb1 = *(const ushort8v*)(kba + 32768 + 16);
        float ac1 = 0.f, ac2 = 0.f;
        #pragma unroll
        for (int j = 0; j < 8; ++j){
          {
            float Fa = h2f(ka0[j]), Fb = h2f(kb0[j]);
            float Da = fmaf(Ereg[j]*Fa, Fa, 1.f);
            float Db = fmaf(Ereg[j]*Fb, Fb, 1.f);
            float R = __builtin_amdgcn_rcpf(Da*Db);
            ac1 = fmaf(vreg[j], R*Db, ac1);     // v * (1/Da)
            ac2 = fmaf(vreg[j], R*Da, ac2);
          }
          {
            float Fa = h2f(ka1[j]), Fb = h2f(kb1[j]);
            float Da = fmaf(Ereg[8+j]*Fa, Fa, 1.f);
            float Db = fmaf(Ereg[8+j]*Fb, Fb, 1.f);
            float R = __builtin_amdgcn_rcpf(Da*Db);
            ac1 = fmaf(vreg[8+j], R*Db, ac1);
            ac2 = fmaf(vreg[8+j], R*Da, ac2);
          }
        }
        float p1 = fmaf(-2.f, ac1, Vsum);       // sum v*tanh for sa
        float p2 = fmaf(-2.f, ac2, Vsum);       // for sb
        p1 += __shfl_xor(p1, 1); p1 += __shfl_xor(p1, 2); p1 += __shfl_xor(p1, 4);
        p2 += __shfl_xor(p2, 1); p2 += __shfl_xor(p2, 2); p2 += __shfl_xor(p2, 4);
        float e1 = 0.f, e2 = 0.f;
        if (sa < t){ e1 = __builtin_amdgcn_exp2f(p1 * LOG2E); if (cg == 0) scores_e[sa] = e1; }
        if (sb < t){ e2 = __builtin_amdgcn_exp2f(p2 * LOG2E); if (cg == 0) scores_e[sb] = e2; }
        float esum = e1 + e2;
        esum += __shfl_xor(esum, 8); esum += __shfl_xor(esum, 16); esum += __shfl_xor(esum, 32);
        if (lane == 0) pp[wv] = esum;
      }
      __syncthreads();  // S2

      // ---- phase 3: ctx col pair (2cp,2cp+1), 16-way s-striping ----
      {
        float4 p0 = ((const float4*)pp)[0], p1v = ((const float4*)pp)[1];
        float4 p2v = ((const float4*)pp)[2], p3 = ((const float4*)pp)[3];
        float sum = (p0.x+p0.y+p0.z+p0.w) + (p1v.x+p1v.y+p1v.z+p1v.w)
                  + (p2v.x+p2v.y+p2v.z+p2v.w) + (p3.x+p3.y+p3.z+p3.w);
        float invZ = __builtin_amdgcn_rcpf(sum);
        const int cg3 = cg & 3, cg4 = cg >> 2;
        const int sgx = sg + 8*cg4;           // 0..15
        const int cp  = wv*4 + cg3;           // 0..63 -> cols 2cp,2cp+1
        const int chunkL = wv >> 1;
        const int inner  = ((wv & 1) << 4) + (cg3 << 2);
        float a0 = 0.f, a1 = 0.f;
        for (int s = sgx; s < t; s += 16){
          int phys = (chunkL ^ ((s ^ (s>>4)) & 7)) & 7;
          unsigned hv = *(const unsigned*)(hidB + s*256 + (phys<<5) + inner);
          float e = scores_e[s];
          float2 hf = __half22float2(__builtin_bit_cast(__half2, hv));
          a0 = fmaf(e, hf.x, a0); a1 = fmaf(e, hf.y, a1);
        }
        a0 += __shfl_xor(a0, 4); a0 += __shfl_xor(a0, 8); a0 += __shfl_xor(a0, 16); a0 += __shfl_xor(a0, 32);
        a1 += __shfl_xor(a1, 4); a1 += __shfl_xor(a1, 8); a1 += __shfl_xor(a1, 16); a1 += __shfl_xor(a1, 32);
        if (sgx == 0){
          int c0 = 2*cp;
          float2 w2 = { a0 * invZ, a1 * invZ };
          *(float2*)&ctx_pad[c0 + (c0>>4)*4] = w2;
        }
      }
      __syncthreads();  // S3
    }

    // ---- phase 4: h_new = tanh(ex + hh + ctx@Wc) ----
    {
      float ac = 0.f;
      const float4* ct4 = (const float4*)(ctx_pad + rg*20);
      #pragma unroll
      for (int i4 = 0; i4 < 4; ++i4){
        float4 cv = ct4[i4];
        ac += cv.x*Wc[i4*4+0] + cv.y*Wc[i4*4+1] + cv.z*Wc[i4*4+2] + cv.w*Wc[i4*4+3];
      }
      #pragma unroll
      for (int m = 1; m < 8; m <<= 1) ac += __shfl_xor(ac, m);
      if (rg == 0){
        float pre = exv + hh_lds[c_] + ac;
        float hn = tanhfast(pre);
        h_pad[c_ + (c_>>4)*4] = hn;
        *(unsigned short*)(hidB + t*256 +
            (((c_>>4) ^ ((t ^ (t>>4)) & 7)) << 5) + ((c_&15)<<1)) = f2h(hn);
        out_bf[((long)b*TLEN + t)*HD + c_] = f2bf(hn);
        if (t == TLEN-1) h_final[b*HD + c_] = hn;
      }
    }
    __syncthreads();  // S4
  }
}

// ---------------- logits GEMM: [2048,128]bf16 @ Wbt[32000,128]^T + bias ----------------
__launch_bounds__(256, 2)
__global__ void gemm_kernel(const unsigned short* __restrict__ A, const unsigned short* __restrict__ Bt,
                            const float* __restrict__ bias, float* __restrict__ C){
  __shared__ char sAB[65536];
  char* sA = sAB;
  char* sB = sAB + 32768;
  const int tid = threadIdx.x;
  const int lane = tid & 63, wv = tid >> 6;
  const int n0 = blockIdx.x * 128, m0 = blockIdx.y * 128;
  const char* Ab = (const char*)A + (long)m0 * 256;
  const char* Bb = (const char*)Bt + (long)n0 * 256;

  #pragma unroll
  for (int it = 0; it < 8; ++it){
    int p  = it*4096 + wv*1024 + lane*16;
    int ps = p ^ (((p >> 8) & 7) << 4);
    gload_lds16(Ab + ps, sA + it*4096 + wv*1024);
    gload_lds16(Bb + ps, sB + it*4096 + wv*1024);
  }
  __syncthreads();

  f32x4 acc[2][8] = {};
  const int r15 = lane & 15, r4 = lane >> 4;
  #pragma unroll
  for (int kk = 0; kk < 4; ++kk){
    short8v af[2], bfr[8];
    #pragma unroll
    for (int mi = 0; mi < 2; ++mi){
      int row = wv*32 + mi*16 + r15;
      int off = row*256 + kk*64 + r4*16;
      af[mi] = *(const short8v*)(sA + (off ^ ((row & 7) << 4)));
    }
    #pragma unroll
    for (int ni = 0; ni < 8; ++ni){
      int row = ni*16 + r15;
      int off = row*256 + kk*64 + r4*16;
      bfr[ni] = *(const short8v*)(sB + (off ^ ((row & 7) << 4)));
    }
    #pragma unroll
    for (int ni = 0; ni < 8; ++ni)
      #pragma unroll
      for (int mi = 0; mi < 2; ++mi)
        acc[mi][ni] = __builtin_amdgcn_mfma_f32_16x16x32_bf16(af[mi], bfr[ni], acc[mi][ni], 0, 0, 0);
  }

  #pragma unroll
  for (int mi = 0; mi < 2; ++mi){
    int rbase = m0 + wv*32 + mi*16 + r4*4;
    #pragma unroll
    for (int ni = 0; ni < 8; ++ni){
      int col = n0 + ni*16 + r15;
      float bv = bias[col];
      #pragma unroll
      for (int j = 0; j < 4; ++j)
        C[(long)(rbase + j) * VOCAB + col] = acc[mi][ni][j] + bv;
    }
  }
}

extern "C" void kernel_launch(void* const* d_in, const int* in_sizes, int n_in,
                              void* d_out, int out_size, void* d_ws, size_t ws_size,
                              hipStream_t stream){
  const int*   x      = (const int*)d_in[0];
  const float* emb    = (const float*)d_in[1];
  const float* W_attn = (const float*)d_in[2];
  const float* U_attn = (const float*)d_in[3];
  const float* v_attn = (const float*)d_in[4];
  const float* W_ih   = (const float*)d_in[5];
  const float* b_ih   = (const float*)d_in[6];
  const float* W_hh   = (const float*)d_in[7];
  const float* b_hh   = (const float*)d_in[8];
  const float* W_out  = (const float*)d_in[9];
  const float* b_out  = (const float*)d_in[10];

  float* logits  = (float*)d_out;
  float* h_final = logits + (long)BATCH * TLEN * VOCAB;

  char* ws = (char*)d_ws;
  float*          ex   = (float*)ws;                                // 1 MB
  unsigned short* Wbt  = (unsigned short*)(ws + 1048576);           // 8.192 MB
  unsigned short* outb = (unsigned short*)(ws + 1048576 + 8192000); // 0.5 MB

  prep_ex_kernel<<<BATCH*TLEN, HD, 0, stream>>>(x, emb, W_ih, b_ih, b_hh, ex);
  prep_wt_kernel<<<dim3(VOCAB/32, HD/32), 256, 0, stream>>>(W_out, Wbt);

  const int ldsBytes = 131072 + 1040*4;   // 135,232 B
  hipFuncSetAttribute((const void*)scan_kernel, hipFuncAttributeMaxDynamicSharedMemorySize, ldsBytes);
  scan_kernel<<<BATCH, 1024, ldsBytes, stream>>>(W_attn, U_attn, v_attn, W_ih, W_hh, ex, outb, h_final);

  gemm_kernel<<<dim3(VOCAB/128, (BATCH*TLEN)/128), 256, 0, stream>>>(outb, Wbt, b_out, logits);
}

// Round 7
// 1045.075 us; speedup vs baseline: 1.4472x; 1.4472x over previous
//
#include <hip/hip_runtime.h>
#include <hip/hip_fp16.h>
#include <hip/hip_bf16.h>
#include <cstdint>

#define TLEN  256
#define HD    128
#define BATCH 8
#define VOCAB 32000
#define EMBD  32
#define ROWB  272   // 256B row + 16B pad: start bank rotates 4/row

typedef __attribute__((ext_vector_type(8))) short short8v;
typedef __attribute__((ext_vector_type(8))) unsigned short ushort8v;
typedef __attribute__((ext_vector_type(4))) float f32x4;

__device__ __forceinline__ float tanhfast(float x){
  float e = __builtin_amdgcn_exp2f(x * 2.8853900817779268f);
  return 1.0f - 2.0f * __builtin_amdgcn_rcpf(e + 1.0f);
}
__device__ __forceinline__ unsigned short f2bf(float f){
  unsigned u = __float_as_uint(f);
  return (unsigned short)((u + 0x7fffu + ((u >> 16) & 1u)) >> 16);
}
__device__ __forceinline__ float h2f(unsigned short u){
  return __half2float(__ushort_as_half(u));
}
__device__ __forceinline__ unsigned short f2h(float f){
  return __half_as_ushort(__float2half(f));
}
__device__ __forceinline__ void gload_lds16(const void* g, void* l){
  __builtin_amdgcn_global_load_lds((const __attribute__((address_space(1))) void*)g,
                                   (__attribute__((address_space(3))) void*)l, 16, 0, 0);
}

// ---------------- prep 1: ex[b,t,c] = emb[x[b,t]] @ W_ih[0:32] + b_ih + b_hh ----------------
__global__ void prep_ex_kernel(const int* __restrict__ x, const float* __restrict__ emb,
                               const float* __restrict__ W_ih, const float* __restrict__ b_ih,
                               const float* __restrict__ b_hh, float* __restrict__ ex){
  int bt = blockIdx.x;
  int c  = threadIdx.x;
  int ix = x[bt];
  const float* er = emb + (long)ix * EMBD;
  float acc = b_ih[c] + b_hh[c];
  #pragma unroll
  for (int e = 0; e < EMBD; ++e) acc += er[e] * W_ih[e * HD + c];
  ex[bt * HD + c] = acc;
}

// ---------------- prep 2: Wbt[n][k] = bf16(W_out[k][n]) ----------------
__global__ void prep_wt_kernel(const float* __restrict__ W_out, unsigned short* __restrict__ Wbt){
  __shared__ float tile[32][33];
  int tx = threadIdx.x & 31, ty = threadIdx.x >> 5;
  int n0 = blockIdx.x * 32, k0 = blockIdx.y * 32;
  #pragma unroll
  for (int j = 0; j < 4; ++j){
    int k = ty + j * 8;
    tile[k][tx] = W_out[(long)(k0 + k) * VOCAB + n0 + tx];
  }
  __syncthreads();
  #pragma unroll
  for (int j = 0; j < 4; ++j){
    int n = ty + j * 8;
    Wbt[(long)(n0 + n) * HD + k0 + tx] = f2bf(tile[tx][n]);
  }
}

// ---------------- scan: one workgroup per batch element, 3 barriers/step ----------------
// keysB[s] holds F = e^{k_s} (fp16); hWcB[s] holds h_s @ Wc (fp16). Rows padded to 272B.
// All reads of rows are guarded by s < t, so no zero-init is needed.
__launch_bounds__(1024)
__global__ void scan_kernel(const float* __restrict__ W_attn, const float* __restrict__ U_attn,
                            const float* __restrict__ v_attn, const float* __restrict__ W_ih,
                            const float* __restrict__ W_hh, const float* __restrict__ ex,
                            unsigned short* __restrict__ out_bf, float* __restrict__ h_final){
  extern __shared__ char lds[];
  char* keysB = lds;                       // 256*272 = 69632 B
  char* hWcB  = lds + 69632;               // 69632 B
  float* fbuf   = (float*)(lds + 139264);
  float* E_pad    = fbuf;                  // 160 f32 (pad 4 per 16): e^{2q}
  float* h_pad    = fbuf + 160;            // 160
  float* hh_lds   = fbuf + 320;            // 128
  float* scores_e = fbuf + 448;            // 256
  float* pp       = fbuf + 704;            // 16

  const int b    = blockIdx.x;
  const int tid  = threadIdx.x;
  const int lane = tid & 63, wv = tid >> 6;
  const int c_   = tid >> 3, rg = tid & 7;      // phase-1 mapping
  const int sg   = lane >> 3, cg = lane & 7;    // phase-2 mapping
  const int cg3  = cg & 3;
  const int sgx  = sg + 8*(cg >> 2);            // phase-3: 0..15 s-stripe
  const int cp   = wv*4 + cg3;                  // phase-3: col pair -> cols 2cp,2cp+1

  const float LOG2E = 1.4426950408889634f;
  const float C2F   = 2.8853900817779268f;

  if (tid < HD) hh_lds[tid] = 0.f;

  // ---- stage weights into VGPRs (f32), as round 3 ----
  float Wa[16], Ua[16], Wh[16], Wc[16];
  {
    float* stage = (float*)lds;        // reuse keysB area (64KB < 69.6KB)
    float4* d4 = (float4*)stage;
    {
      const float4* s4 = (const float4*)W_attn;
      for (int i = 0; i < 4; ++i) d4[tid + i*1024] = s4[tid + i*1024];
      __syncthreads();
      #pragma unroll
      for (int i = 0; i < 16; ++i) Wa[i] = stage[(rg*16 + i)*HD + c_];
      __syncthreads();
    }
    {
      const float4* s4 = (const float4*)U_attn;
      for (int i = 0; i < 4; ++i) d4[tid + i*1024] = s4[tid + i*1024];
      __syncthreads();
      #pragma unroll
      for (int i = 0; i < 16; ++i) Ua[i] = stage[(rg*16 + i)*HD + c_];
      __syncthreads();
    }
    {
      const float4* s4 = (const float4*)W_hh;
      for (int i = 0; i < 4; ++i) d4[tid + i*1024] = s4[tid + i*1024];
      __syncthreads();
      #pragma unroll
      for (int i = 0; i < 16; ++i) Wh[i] = stage[(rg*16 + i)*HD + c_];
      __syncthreads();
    }
    {
      const float4* s4 = (const float4*)(W_ih + EMBD*HD);
      for (int i = 0; i < 4; ++i) d4[tid + i*1024] = s4[tid + i*1024];
      __syncthreads();
      #pragma unroll
      for (int i = 0; i < 16; ++i) Wc[i] = stage[(rg*16 + i)*HD + c_];
      __syncthreads();
    }
  }

  // ---- v in registers (cols cg*16..+15, from global) + sum ----
  float vreg[16], Vsum = 0.f;
  {
    const float* vg = v_attn + cg*16;
    #pragma unroll
    for (int i = 0; i < 16; ++i){ vreg[i] = vg[i]; Vsum += vreg[i]; }
  }

  const float* exb = ex + (long)b * TLEN * HD;

  for (int t = 0; t < TLEN; ++t){
    if (t > 0){
      // ---- P1: 4 GEMVs of h: q(->E), k(->F), hh, hWc ----
      {
        float aq = 0.f, ak = 0.f, ah = 0.f, aw = 0.f;
        const float4* h4 = (const float4*)(h_pad + rg*20);
        #pragma unroll
        for (int i4 = 0; i4 < 4; ++i4){
          float4 hv = h4[i4];
          aq += hv.x*Wa[i4*4+0] + hv.y*Wa[i4*4+1] + hv.z*Wa[i4*4+2] + hv.w*Wa[i4*4+3];
          ak += hv.x*Ua[i4*4+0] + hv.y*Ua[i4*4+1] + hv.z*Ua[i4*4+2] + hv.w*Ua[i4*4+3];
          ah += hv.x*Wh[i4*4+0] + hv.y*Wh[i4*4+1] + hv.z*Wh[i4*4+2] + hv.w*Wh[i4*4+3];
          aw += hv.x*Wc[i4*4+0] + hv.y*Wc[i4*4+1] + hv.z*Wc[i4*4+2] + hv.w*Wc[i4*4+3];
        }
        #pragma unroll
        for (int m = 1; m < 8; m <<= 1){
          aq += __shfl_xor(aq, m); ak += __shfl_xor(ak, m);
          ah += __shfl_xor(ah, m); aw += __shfl_xor(aw, m);
        }
        if (rg == 0){
          E_pad[c_ + (c_>>4)*4] = __builtin_amdgcn_exp2f(aq * C2F);      // e^{2q}
          hh_lds[c_] = ah;
          int s = t - 1;
          float F = fminf(__builtin_amdgcn_exp2f(ak * LOG2E), 60000.f);  // e^k
          *(unsigned short*)(keysB + s*ROWB + c_*2) = f2h(F);
          *(unsigned short*)(hWcB  + s*ROWB + c_*2) = f2h(aw);
        }
      }
      __syncthreads();  // S1

      // ---- P2: e_s = exp(v . tanh(q+k_s));  tanh = 1 - 2/(1 + E*F^2) ----
      {
        float Ereg[16];
        {
          const float4* E4 = (const float4*)(E_pad + cg*20);
          #pragma unroll
          for (int i = 0; i < 4; ++i){
            float4 ev = E4[i];
            Ereg[i*4+0]=ev.x; Ereg[i*4+1]=ev.y; Ereg[i*4+2]=ev.z; Ereg[i*4+3]=ev.w;
          }
        }
        float esum = 0.f;
        #pragma unroll
        for (int it = 0; it < 2; ++it){
          int s = wv*8 + sg + it*128;
          float e = 0.f;
          if (s < t){
            const char* kb = keysB + s*ROWB + cg*32;
            ushort8v k0 = *(const ushort8v*)kb;
            ushort8v k1 = *(const ushort8v*)(kb + 16);
            float ac = 0.f;
            #pragma unroll
            for (int j = 0; j < 8; ++j){
              float F0 = h2f(k0[j]);
              float D0 = fmaf(Ereg[j]*F0, F0, 1.f);
              ac = fmaf(vreg[j], __builtin_amdgcn_rcpf(D0), ac);
              float F1 = h2f(k1[j]);
              float D1 = fmaf(Ereg[8+j]*F1, F1, 1.f);
              ac = fmaf(vreg[8+j], __builtin_amdgcn_rcpf(D1), ac);
            }
            float p = fmaf(-2.f, ac, Vsum);            // v . tanh
            p += __shfl_xor(p, 1); p += __shfl_xor(p, 2); p += __shfl_xor(p, 4);
            e = __builtin_amdgcn_exp2f(p * LOG2E);
            if (cg == 0) scores_e[s] = e;
          }
          esum += e;
        }
        esum += __shfl_xor(esum, 8); esum += __shfl_xor(esum, 16); esum += __shfl_xor(esum, 32);
        if (lane == 0) pp[wv] = esum;
      }
      __syncthreads();  // S2
    }

    // ---- P3: ctxWc[col] = (sum_s e_s * hWc[s][col]) / Z, then h_new inline ----
    {
      float4 p0 = ((const float4*)pp)[0], p1v = ((const float4*)pp)[1];
      float4 p2v = ((const float4*)pp)[2], p3 = ((const float4*)pp)[3];
      float sum = (p0.x+p0.y+p0.z+p0.w) + (p1v.x+p1v.y+p1v.z+p1v.w)
                + (p2v.x+p2v.y+p2v.z+p2v.w) + (p3.x+p3.y+p3.z+p3.w);
      float invZ = __builtin_amdgcn_rcpf(sum);         // garbage at t=0, selected away
      float a0 = 0.f, a1 = 0.f;
      const char* hb = hWcB + cp*4;
      for (int s = sgx; s < t; s += 16){
        float e = scores_e[s];
        unsigned hv = *(const unsigned*)(hb + s*ROWB);
        float2 hf = __half22float2(__builtin_bit_cast(__half2, hv));
        a0 = fmaf(e, hf.x, a0); a1 = fmaf(e, hf.y, a1);
      }
      a0 += __shfl_xor(a0, 4); a0 += __shfl_xor(a0, 8); a0 += __shfl_xor(a0, 16); a0 += __shfl_xor(a0, 32);
      a1 += __shfl_xor(a1, 4); a1 += __shfl_xor(a1, 8); a1 += __shfl_xor(a1, 16); a1 += __shfl_xor(a1, 32);
      if (sgx == 0){
        float cw0 = (t > 0) ? a0 * invZ : 0.f;
        float cw1 = (t > 0) ? a1 * invZ : 0.f;
        int c0 = 2*cp;
        float2 ev  = *(const float2*)(exb + t*HD + c0);
        float2 hhv = *(const float2*)(&hh_lds[c0]);
        float h0 = tanhfast(ev.x + hhv.x + cw0);
        float h1 = tanhfast(ev.y + hhv.y + cw1);
        float2 hw = { h0, h1 };
        *(float2*)&h_pad[c0 + (c0>>4)*4] = hw;
        unsigned po = (unsigned)f2bf(h0) | ((unsigned)f2bf(h1) << 16);
        *(unsigned*)(&out_bf[((long)b*TLEN + t)*HD + c0]) = po;
        if (t == TLEN-1) *(float2*)&h_final[b*HD + c0] = hw;
      }
    }
    __syncthreads();  // S3: h visible for next step's P1
  }
}

// ---------------- logits GEMM: [2048,128]bf16 @ Wbt[32000,128]^T + bias ----------------
__launch_bounds__(256, 2)
__global__ void gemm_kernel(const unsigned short* __restrict__ A, const unsigned short* __restrict__ Bt,
                            const float* __restrict__ bias, float* __restrict__ C){
  __shared__ char sAB[65536];
  char* sA = sAB;
  char* sB = sAB + 32768;
  const int tid = threadIdx.x;
  const int lane = tid & 63, wv = tid >> 6;
  const int n0 = blockIdx.x * 128, m0 = blockIdx.y * 128;
  const char* Ab = (const char*)A + (long)m0 * 256;
  const char* Bb = (const char*)Bt + (long)n0 * 256;

  #pragma unroll
  for (int it = 0; it < 8; ++it){
    int p  = it*4096 + wv*1024 + lane*16;
    int ps = p ^ (((p >> 8) & 7) << 4);
    gload_lds16(Ab + ps, sA + it*4096 + wv*1024);
    gload_lds16(Bb + ps, sB + it*4096 + wv*1024);
  }
  __syncthreads();

  f32x4 acc[2][8] = {};
  const int r15 = lane & 15, r4 = lane >> 4;
  #pragma unroll
  for (int kk = 0; kk < 4; ++kk){
    short8v af[2], bfr[8];
    #pragma unroll
    for (int mi = 0; mi < 2; ++mi){
      int row = wv*32 + mi*16 + r15;
      int off = row*256 + kk*64 + r4*16;
      af[mi] = *(const short8v*)(sA + (off ^ ((row & 7) << 4)));
    }
    #pragma unroll
    for (int ni = 0; ni < 8; ++ni){
      int row = ni*16 + r15;
      int off = row*256 + kk*64 + r4*16;
      bfr[ni] = *(const short8v*)(sB + (off ^ ((row & 7) << 4)));
    }
    #pragma unroll
    for (int ni = 0; ni < 8; ++ni)
      #pragma unroll
      for (int mi = 0; mi < 2; ++mi)
        acc[mi][ni] = __builtin_amdgcn_mfma_f32_16x16x32_bf16(af[mi], bfr[ni], acc[mi][ni], 0, 0, 0);
  }

  #pragma unroll
  for (int mi = 0; mi < 2; ++mi){
    int rbase = m0 + wv*32 + mi*16 + r4*4;
    #pragma unroll
    for (int ni = 0; ni < 8; ++ni){
      int col = n0 + ni*16 + r15;
      float bv = bias[col];
      #pragma unroll
      for (int j = 0; j < 4; ++j)
        C[(long)(rbase + j) * VOCAB + col] = acc[mi][ni][j] + bv;
    }
  }
}

extern "C" void kernel_launch(void* const* d_in, const int* in_sizes, int n_in,
                              void* d_out, int out_size, void* d_ws, size_t ws_size,
                              hipStream_t stream){
  const int*   x      = (const int*)d_in[0];
  const float* emb    = (const float*)d_in[1];
  const float* W_attn = (const float*)d_in[2];
  const float* U_attn = (const float*)d_in[3];
  const float* v_attn = (const float*)d_in[4];
  const float* W_ih   = (const float*)d_in[5];
  const float* b_ih   = (const float*)d_in[6];
  const float* W_hh   = (const float*)d_in[7];
  const float* b_hh   = (const float*)d_in[8];
  const float* W_out  = (const float*)d_in[9];
  const float* b_out  = (const float*)d_in[10];

  float* logits  = (float*)d_out;
  float* h_final = logits + (long)BATCH * TLEN * VOCAB;

  char* ws = (char*)d_ws;
  float*          ex   = (float*)ws;                                // 1 MB
  unsigned short* Wbt  = (unsigned short*)(ws + 1048576);           // 8.192 MB
  unsigned short* outb = (unsigned short*)(ws + 1048576 + 8192000); // 0.5 MB

  prep_ex_kernel<<<BATCH*TLEN, HD, 0, stream>>>(x, emb, W_ih, b_ih, b_hh, ex);
  prep_wt_kernel<<<dim3(VOCAB/32, HD/32), 256, 0, stream>>>(W_out, Wbt);

  const int ldsBytes = 139264 + 720*4;   // 142,144 B
  hipFuncSetAttribute((const void*)scan_kernel, hipFuncAttributeMaxDynamicSharedMemorySize, ldsBytes);
  scan_kernel<<<BATCH, 1024, ldsBytes, stream>>>(W_attn, U_attn, v_attn, W_ih, W_hh, ex, outb, h_final);

  gemm_kernel<<<dim3(VOCAB/128, (BATCH*TLEN)/128), 256, 0, stream>>>(outb, Wbt, b_out, logits);
}

// Round 8
// 923.492 us; speedup vs baseline: 1.6377x; 1.1317x over previous
//
#include <hip/hip_runtime.h>
#include <hip/hip_fp16.h>
#include <hip/hip_bf16.h>
#include <cstdint>

#define TLEN  256
#define HD    128
#define BATCH 8
#define VOCAB 32000
#define EMBD  32
#define ROWB  272   // 256B row + 16B pad

typedef __attribute__((ext_vector_type(8))) short short8v;
typedef __attribute__((ext_vector_type(8))) unsigned short ushort8v;
typedef __attribute__((ext_vector_type(4))) float f32x4;

__device__ __forceinline__ float tanhfast(float x){
  float e = __builtin_amdgcn_exp2f(x * 2.8853900817779268f);
  return 1.0f - 2.0f * __builtin_amdgcn_rcpf(e + 1.0f);
}
__device__ __forceinline__ unsigned short f2bf(float f){
  unsigned u = __float_as_uint(f);
  return (unsigned short)((u + 0x7fffu + ((u >> 16) & 1u)) >> 16);
}
__device__ __forceinline__ float h2f(unsigned short u){
  return __half2float(__ushort_as_half(u));
}
__device__ __forceinline__ unsigned short f2h(float f){
  return __half_as_ushort(__float2half(f));
}
__device__ __forceinline__ void gload_lds16(const void* g, void* l){
  __builtin_amdgcn_global_load_lds((const __attribute__((address_space(1))) void*)g,
                                   (__attribute__((address_space(3))) void*)l, 16, 0, 0);
}

// ---- fast cross-lane adds: DPP quad_perm for xor1/xor2, ds_swizzle for 4/8/16 ----
__device__ __forceinline__ float dpp_add1(float x){   // + lane^1
  int y = __builtin_amdgcn_mov_dpp(__float_as_int(x), 0xB1, 0xF, 0xF, true);
  return x + __int_as_float(y);
}
__device__ __forceinline__ float dpp_add2(float x){   // + lane^2
  int y = __builtin_amdgcn_mov_dpp(__float_as_int(x), 0x4E, 0xF, 0xF, true);
  return x + __int_as_float(y);
}
__device__ __forceinline__ float swz_add4(float x){   // + lane^4
  int y = __builtin_amdgcn_ds_swizzle(__float_as_int(x), 0x101F);
  return x + __int_as_float(y);
}
__device__ __forceinline__ float swz_add8(float x){   // + lane^8
  int y = __builtin_amdgcn_ds_swizzle(__float_as_int(x), 0x201F);
  return x + __int_as_float(y);
}
__device__ __forceinline__ float swz_add16(float x){  // + lane^16
  int y = __builtin_amdgcn_ds_swizzle(__float_as_int(x), 0x401F);
  return x + __int_as_float(y);
}

// ---------------- prep 1: ex[b,t,c] = emb[x[b,t]] @ W_ih[0:32] + b_ih + b_hh ----------------
__global__ void prep_ex_kernel(const int* __restrict__ x, const float* __restrict__ emb,
                               const float* __restrict__ W_ih, const float* __restrict__ b_ih,
                               const float* __restrict__ b_hh, float* __restrict__ ex){
  int bt = blockIdx.x;
  int c  = threadIdx.x;
  int ix = x[bt];
  const float* er = emb + (long)ix * EMBD;
  float acc = b_ih[c] + b_hh[c];
  #pragma unroll
  for (int e = 0; e < EMBD; ++e) acc += er[e] * W_ih[e * HD + c];
  ex[bt * HD + c] = acc;
}

// ---------------- prep 2: Wbt[n][k] = bf16(W_out[k][n]) ----------------
__global__ void prep_wt_kernel(const float* __restrict__ W_out, unsigned short* __restrict__ Wbt){
  __shared__ float tile[32][33];
  int tx = threadIdx.x & 31, ty = threadIdx.x >> 5;
  int n0 = blockIdx.x * 32, k0 = blockIdx.y * 32;
  #pragma unroll
  for (int j = 0; j < 4; ++j){
    int k = ty + j * 8;
    tile[k][tx] = W_out[(long)(k0 + k) * VOCAB + n0 + tx];
  }
  __syncthreads();
  #pragma unroll
  for (int j = 0; j < 4; ++j){
    int n = ty + j * 8;
    Wbt[(long)(n0 + n) * HD + k0 + tx] = f2bf(tile[tx][n]);
  }
}

// ---------------- scan: one workgroup per batch element, 3 barriers/step ----------------
// keysB[s] holds G = e^{2 k_s} (fp16); hWcB[s] holds h_s @ Wc (fp16). Rows 272B.
// All row reads guarded by s < t -> no zero-init needed.
__launch_bounds__(1024)
__global__ void scan_kernel(const float* __restrict__ W_attn, const float* __restrict__ U_attn,
                            const float* __restrict__ v_attn, const float* __restrict__ W_ih,
                            const float* __restrict__ W_hh, const float* __restrict__ ex,
                            unsigned short* __restrict__ out_bf, float* __restrict__ h_final){
  extern __shared__ char lds[];
  char* keysB = lds;                       // 256*272 = 69632 B
  char* hWcB  = lds + 69632;               // 69632 B
  float* fbuf   = (float*)(lds + 139264);
  float* E_pad    = fbuf;                  // 160 f32 (pad 4 per 16): e^{2q}
  float* h_pad    = fbuf + 160;            // 160
  float* hh_lds   = fbuf + 320;            // 128
  float* scores_e = fbuf + 448;            // 256
  float* pp       = fbuf + 704;            // 16

  const int b    = blockIdx.x;
  const int tid  = threadIdx.x;
  const int lane = tid & 63, wv = tid >> 6;
  const int c_   = tid >> 3, rg = tid & 7;      // phase-1 mapping
  const int sg   = lane >> 3, cg = lane & 7;    // phase-2 mapping
  const int cg3  = cg & 3;
  const int sgx  = sg + 8*(cg >> 2);            // phase-3: 0..15 s-stripe
  const int cp   = wv*4 + cg3;                  // phase-3: col pair -> cols 2cp,2cp+1

  const float LOG2E = 1.4426950408889634f;
  const float C2F   = 2.8853900817779268f;

  if (tid < HD) hh_lds[tid] = 0.f;

  // ---- stage weights into VGPRs (f32) ----
  float Wa[16], Ua[16], Wh[16], Wc[16];
  {
    float* stage = (float*)lds;        // reuse keysB area
    float4* d4 = (float4*)stage;
    {
      const float4* s4 = (const float4*)W_attn;
      for (int i = 0; i < 4; ++i) d4[tid + i*1024] = s4[tid + i*1024];
      __syncthreads();
      #pragma unroll
      for (int i = 0; i < 16; ++i) Wa[i] = stage[(rg*16 + i)*HD + c_];
      __syncthreads();
    }
    {
      const float4* s4 = (const float4*)U_attn;
      for (int i = 0; i < 4; ++i) d4[tid + i*1024] = s4[tid + i*1024];
      __syncthreads();
      #pragma unroll
      for (int i = 0; i < 16; ++i) Ua[i] = stage[(rg*16 + i)*HD + c_];
      __syncthreads();
    }
    {
      const float4* s4 = (const float4*)W_hh;
      for (int i = 0; i < 4; ++i) d4[tid + i*1024] = s4[tid + i*1024];
      __syncthreads();
      #pragma unroll
      for (int i = 0; i < 16; ++i) Wh[i] = stage[(rg*16 + i)*HD + c_];
      __syncthreads();
    }
    {
      const float4* s4 = (const float4*)(W_ih + EMBD*HD);
      for (int i = 0; i < 4; ++i) d4[tid + i*1024] = s4[tid + i*1024];
      __syncthreads();
      #pragma unroll
      for (int i = 0; i < 16; ++i) Wc[i] = stage[(rg*16 + i)*HD + c_];
      __syncthreads();
    }
  }

  // ---- v in registers (cols cg*16..+15) + FULL 128-sum (cg-reduce), pre-scaled ----
  float vreg[16], VsumL;
  {
    const float* vg = v_attn + cg*16;
    float s = 0.f;
    #pragma unroll
    for (int i = 0; i < 16; ++i){ vreg[i] = vg[i]; s += vreg[i]; }
    s = dpp_add1(s); s = dpp_add2(s); s = swz_add4(s);   // full sum over all 128
    VsumL = s * LOG2E;
  }

  const float* exb = ex + (long)b * TLEN * HD;

  for (int t = 0; t < TLEN; ++t){
    if (t > 0){
      // ---- P1: 4 GEMVs of h: q(->E=e^{2q}), k(->G=e^{2k}), hh, hWc ----
      {
        float aq = 0.f, ak = 0.f, ah = 0.f, aw = 0.f;
        const float4* h4 = (const float4*)(h_pad + rg*20);
        #pragma unroll
        for (int i4 = 0; i4 < 4; ++i4){
          float4 hv = h4[i4];
          aq += hv.x*Wa[i4*4+0] + hv.y*Wa[i4*4+1] + hv.z*Wa[i4*4+2] + hv.w*Wa[i4*4+3];
          ak += hv.x*Ua[i4*4+0] + hv.y*Ua[i4*4+1] + hv.z*Ua[i4*4+2] + hv.w*Ua[i4*4+3];
          ah += hv.x*Wh[i4*4+0] + hv.y*Wh[i4*4+1] + hv.z*Wh[i4*4+2] + hv.w*Wh[i4*4+3];
          aw += hv.x*Wc[i4*4+0] + hv.y*Wc[i4*4+1] + hv.z*Wc[i4*4+2] + hv.w*Wc[i4*4+3];
        }
        aq = dpp_add1(aq); aq = dpp_add2(aq); aq = swz_add4(aq);
        ak = dpp_add1(ak); ak = dpp_add2(ak); ak = swz_add4(ak);
        ah = dpp_add1(ah); ah = dpp_add2(ah); ah = swz_add4(ah);
        aw = dpp_add1(aw); aw = dpp_add2(aw); aw = swz_add4(aw);
        if (rg == 0){
          E_pad[c_ + (c_>>4)*4] = __builtin_amdgcn_exp2f(aq * C2F);      // e^{2q}
          hh_lds[c_] = ah;
          int s = t - 1;
          float G = fminf(__builtin_amdgcn_exp2f(ak * C2F), 60000.f);    // e^{2k}
          *(unsigned short*)(keysB + s*ROWB + c_*2) = f2h(G);
          *(unsigned short*)(hWcB  + s*ROWB + c_*2) = f2h(aw);
        }
      }
      __syncthreads();  // S1

      // ---- P2: e_s = exp(v . tanh(q+k_s));  tanh = 1 - 2/(1 + E*G), quad-rcp ----
      {
        float Ereg[16];
        {
          const float4* E4 = (const float4*)(E_pad + cg*20);
          #pragma unroll
          for (int i = 0; i < 4; ++i){
            float4 ev = E4[i];
            Ereg[i*4+0]=ev.x; Ereg[i*4+1]=ev.y; Ereg[i*4+2]=ev.z; Ereg[i*4+3]=ev.w;
          }
        }
        float e1 = 0.f, e2 = 0.f;
        #pragma unroll
        for (int it = 0; it < 2; ++it){
          int s = wv*8 + sg + it*128;
          if (s < t){
            const char* kb = keysB + s*ROWB + cg*32;
            ushort8v g0 = *(const ushort8v*)kb;
            ushort8v g1 = *(const ushort8v*)(kb + 16);
            float ac = 0.f;
            #pragma unroll
            for (int jj = 0; jj < 4; ++jj){
              float D0 = fmaf(Ereg[2*jj],     h2f(g0[2*jj]),   1.f);
              float D1 = fmaf(Ereg[2*jj+1],   h2f(g0[2*jj+1]), 1.f);
              float D2 = fmaf(Ereg[8+2*jj],   h2f(g1[2*jj]),   1.f);
              float D3 = fmaf(Ereg[8+2*jj+1], h2f(g1[2*jj+1]), 1.f);
              float P01 = D0*D1, P23 = D2*D3;
              float R   = __builtin_amdgcn_rcpf(P01*P23);
              float R01 = R*P23, R23 = R*P01;
              ac = fmaf(vreg[2*jj],     R01*D1, ac);
              ac = fmaf(vreg[2*jj+1],   R01*D0, ac);
              ac = fmaf(vreg[8+2*jj],   R23*D3, ac);
              ac = fmaf(vreg[8+2*jj+1], R23*D2, ac);
            }
            ac = dpp_add1(ac); ac = dpp_add2(ac); ac = swz_add4(ac);   // cg-reduce
            float e = __builtin_amdgcn_exp2f(fmaf(-C2F, ac, VsumL));
            if (cg == 0) scores_e[s] = e;
            if (it == 0) e1 = e; else e2 = e;
          }
        }
        float esum = e1 + e2;
        esum = swz_add8(esum); esum = swz_add16(esum); esum += __shfl_xor(esum, 32);
        if (lane == 0) pp[wv] = esum;
      }
      __syncthreads();  // S2
    }

    // ---- P3: ctxWc[col] = (sum_s e_s * hWc[s][col]) / Z, then h_new inline ----
    {
      float4 p0 = ((const float4*)pp)[0], p1v = ((const float4*)pp)[1];
      float4 p2v = ((const float4*)pp)[2], p3 = ((const float4*)pp)[3];
      float sum = (p0.x+p0.y+p0.z+p0.w) + (p1v.x+p1v.y+p1v.z+p1v.w)
                + (p2v.x+p2v.y+p2v.z+p2v.w) + (p3.x+p3.y+p3.z+p3.w);
      float invZ = __builtin_amdgcn_rcpf(sum);         // garbage at t=0, selected away
      float a0 = 0.f, a1 = 0.f;
      const char* hb = hWcB + cp*4;
      for (int s = sgx; s < t; s += 16){
        float e = scores_e[s];
        unsigned hv = *(const unsigned*)(hb + s*ROWB);
        float2 hf = __half22float2(__builtin_bit_cast(__half2, hv));
        a0 = fmaf(e, hf.x, a0); a1 = fmaf(e, hf.y, a1);
      }
      a0 = swz_add4(a0); a0 = swz_add8(a0); a0 = swz_add16(a0); a0 += __shfl_xor(a0, 32);
      a1 = swz_add4(a1); a1 = swz_add8(a1); a1 = swz_add16(a1); a1 += __shfl_xor(a1, 32);
      if (sgx == 0){
        float cw0 = (t > 0) ? a0 * invZ : 0.f;
        float cw1 = (t > 0) ? a1 * invZ : 0.f;
        int c0 = 2*cp;
        float2 ev  = *(const float2*)(exb + t*HD + c0);
        float2 hhv = *(const float2*)(&hh_lds[c0]);
        float h0 = tanhfast(ev.x + hhv.x + cw0);
        float h1 = tanhfast(ev.y + hhv.y + cw1);
        float2 hw = { h0, h1 };
        *(float2*)&h_pad[c0 + (c0>>4)*4] = hw;
        unsigned po = (unsigned)f2bf(h0) | ((unsigned)f2bf(h1) << 16);
        *(unsigned*)(&out_bf[((long)b*TLEN + t)*HD + c0]) = po;
        if (t == TLEN-1) *(float2*)&h_final[b*HD + c0] = hw;
      }
    }
    __syncthreads();  // S3: h visible for next step's P1
  }
}

// ---------------- logits GEMM: [2048,128]bf16 @ Wbt[32000,128]^T + bias ----------------
__launch_bounds__(256, 2)
__global__ void gemm_kernel(const unsigned short* __restrict__ A, const unsigned short* __restrict__ Bt,
                            const float* __restrict__ bias, float* __restrict__ C){
  __shared__ char sAB[65536];
  char* sA = sAB;
  char* sB = sAB + 32768;
  const int tid = threadIdx.x;
  const int lane = tid & 63, wv = tid >> 6;
  const int n0 = blockIdx.x * 128, m0 = blockIdx.y * 128;
  const char* Ab = (const char*)A + (long)m0 * 256;
  const char* Bb = (const char*)Bt + (long)n0 * 256;

  #pragma unroll
  for (int it = 0; it < 8; ++it){
    int p  = it*4096 + wv*1024 + lane*16;
    int ps = p ^ (((p >> 8) & 7) << 4);
    gload_lds16(Ab + ps, sA + it*4096 + wv*1024);
    gload_lds16(Bb + ps, sB + it*4096 + wv*1024);
  }
  __syncthreads();

  f32x4 acc[2][8] = {};
  const int r15 = lane & 15, r4 = lane >> 4;
  #pragma unroll
  for (int kk = 0; kk < 4; ++kk){
    short8v af[2], bfr[8];
    #pragma unroll
    for (int mi = 0; mi < 2; ++mi){
      int row = wv*32 + mi*16 + r15;
      int off = row*256 + kk*64 + r4*16;
      af[mi] = *(const short8v*)(sA + (off ^ ((row & 7) << 4)));
    }
    #pragma unroll
    for (int ni = 0; ni < 8; ++ni){
      int row = ni*16 + r15;
      int off = row*256 + kk*64 + r4*16;
      bfr[ni] = *(const short8v*)(sB + (off ^ ((row & 7) << 4)));
    }
    #pragma unroll
    for (int ni = 0; ni < 8; ++ni)
      #pragma unroll
      for (int mi = 0; mi < 2; ++mi)
        acc[mi][ni] = __builtin_amdgcn_mfma_f32_16x16x32_bf16(af[mi], bfr[ni], acc[mi][ni], 0, 0, 0);
  }

  #pragma unroll
  for (int mi = 0; mi < 2; ++mi){
    int rbase = m0 + wv*32 + mi*16 + r4*4;
    #pragma unroll
    for (int ni = 0; ni < 8; ++ni){
      int col = n0 + ni*16 + r15;
      float bv = bias[col];
      #pragma unroll
      for (int j = 0; j < 4; ++j)
        C[(long)(rbase + j) * VOCAB + col] = acc[mi][ni][j] + bv;
    }
  }
}

extern "C" void kernel_launch(void* const* d_in, const int* in_sizes, int n_in,
                              void* d_out, int out_size, void* d_ws, size_t ws_size,
                              hipStream_t stream){
  const int*   x      = (const int*)d_in[0];
  const float* emb    = (const float*)d_in[1];
  const float* W_attn = (const float*)d_in[2];
  const float* U_attn = (const float*)d_in[3];
  const float* v_attn = (const float*)d_in[4];
  const float* W_ih   = (const float*)d_in[5];
  const float* b_ih   = (const float*)d_in[6];
  const float* W_hh   = (const float*)d_in[7];
  const float* b_hh   = (const float*)d_in[8];
  const float* W_out  = (const float*)d_in[9];
  const float* b_out  = (const float*)d_in[10];

  float* logits  = (float*)d_out;
  float* h_final = logits + (long)BATCH * TLEN * VOCAB;

  char* ws = (char*)d_ws;
  float*          ex   = (float*)ws;                                // 1 MB
  unsigned short* Wbt  = (unsigned short*)(ws + 1048576);           // 8.192 MB
  unsigned short* outb = (unsigned short*)(ws + 1048576 + 8192000); // 0.5 MB

  prep_ex_kernel<<<BATCH*TLEN, HD, 0, stream>>>(x, emb, W_ih, b_ih, b_hh, ex);
  prep_wt_kernel<<<dim3(VOCAB/32, HD/32), 256, 0, stream>>>(W_out, Wbt);

  const int ldsBytes = 139264 + 720*4;   // 142,144 B
  hipFuncSetAttribute((const void*)scan_kernel, hipFuncAttributeMaxDynamicSharedMemorySize, ldsBytes);
  scan_kernel<<<BATCH, 1024, ldsBytes, stream>>>(W_attn, U_attn, v_attn, W_ih, W_hh, ex, outb, h_final);

  gemm_kernel<<<dim3(VOCAB/128, (BATCH*TLEN)/128), 256, 0, stream>>>(outb, Wbt, b_out, logits);
}

// Round 9
// 698.872 us; speedup vs baseline: 2.1641x; 1.3214x over previous
//
#include <hip/hip_runtime.h>
#include <hip/hip_fp16.h>
#include <hip/hip_bf16.h>
#include <cstdint>

#define TLEN  256
#define HD    128
#define BATCH 8
#define VOCAB 32000
#define EMBD  32
#define ROWB  272   // 256B row + 16B pad

typedef __attribute__((ext_vector_type(8))) short short8v;
typedef __attribute__((ext_vector_type(8))) unsigned short ushort8v;
typedef __attribute__((ext_vector_type(4))) float f32x4;
typedef __attribute__((ext_vector_type(2))) _Float16 hv2;

__device__ __forceinline__ float tanhfast(float x){
  float e = __builtin_amdgcn_exp2f(x * 2.8853900817779268f);
  return 1.0f - 2.0f * __builtin_amdgcn_rcpf(e + 1.0f);
}
__device__ __forceinline__ unsigned short f2bf(float f){
  unsigned u = __float_as_uint(f);
  return (unsigned short)((u + 0x7fffu + ((u >> 16) & 1u)) >> 16);
}
__device__ __forceinline__ float h2f(unsigned short u){
  return __half2float(__ushort_as_half(u));
}
__device__ __forceinline__ unsigned short f2h(float f){
  return __half_as_ushort(__float2half(f));
}
__device__ __forceinline__ unsigned pk2(float lo, float hi){
  return __builtin_bit_cast(unsigned, __floats2half2_rn(lo, hi));
}
__device__ __forceinline__ float fdot2u(unsigned a, unsigned b, float c){
#if __has_builtin(__builtin_amdgcn_fdot2)
  return __builtin_amdgcn_fdot2(__builtin_bit_cast(hv2, a), __builtin_bit_cast(hv2, b), c, false);
#else
  float2 fa = __half22float2(__builtin_bit_cast(__half2, a));
  float2 fb = __half22float2(__builtin_bit_cast(__half2, b));
  return c + fa.x*fb.x + fa.y*fb.y;
#endif
}
__device__ __forceinline__ void ld8u(const void* p, unsigned* d){
  uint4 a = *(const uint4*)p;
  uint4 b = *(const uint4*)((const char*)p + 16);
  d[0]=a.x; d[1]=a.y; d[2]=a.z; d[3]=a.w; d[4]=b.x; d[5]=b.y; d[6]=b.z; d[7]=b.w;
}
__device__ __forceinline__ void gload_lds16(const void* g, void* l){
  __builtin_amdgcn_global_load_lds((const __attribute__((address_space(1))) void*)g,
                                   (__attribute__((address_space(3))) void*)l, 16, 0, 0);
}

// ---- cross-lane adds ----
__device__ __forceinline__ float dpp_add1(float x){   // + lane^1 (butterfly)
  int y = __builtin_amdgcn_mov_dpp(__float_as_int(x), 0xB1, 0xF, 0xF, true);
  return x + __int_as_float(y);
}
__device__ __forceinline__ float dpp_add2(float x){   // + lane^2 (butterfly)
  int y = __builtin_amdgcn_mov_dpp(__float_as_int(x), 0x4E, 0xF, 0xF, true);
  return x + __int_as_float(y);
}
__device__ __forceinline__ float dpp_shl4(float x){   // + lane+4 (valid where (l&15)<12)
  int y = __builtin_amdgcn_mov_dpp(__float_as_int(x), 0x104, 0xF, 0xF, true);
  return x + __int_as_float(y);
}
__device__ __forceinline__ float dpp_shl8(float x){   // + lane+8 (valid where (l&15)<8)
  int y = __builtin_amdgcn_mov_dpp(__float_as_int(x), 0x108, 0xF, 0xF, true);
  return x + __int_as_float(y);
}
__device__ __forceinline__ float swz_add4(float x){   // + lane^4 (butterfly)
  int y = __builtin_amdgcn_ds_swizzle(__float_as_int(x), 0x101F);
  return x + __int_as_float(y);
}
__device__ __forceinline__ float swz_add16(float x){  // + lane^16 (butterfly)
  int y = __builtin_amdgcn_ds_swizzle(__float_as_int(x), 0x401F);
  return x + __int_as_float(y);
}

// ---------------- prep 1: ex[b,t,c] = emb[x[b,t]] @ W_ih[0:32] + b_ih + b_hh ----------------
__global__ void prep_ex_kernel(const int* __restrict__ x, const float* __restrict__ emb,
                               const float* __restrict__ W_ih, const float* __restrict__ b_ih,
                               const float* __restrict__ b_hh, float* __restrict__ ex){
  int bt = blockIdx.x;
  int c  = threadIdx.x;
  int ix = x[bt];
  const float* er = emb + (long)ix * EMBD;
  float acc = b_ih[c] + b_hh[c];
  #pragma unroll
  for (int e = 0; e < EMBD; ++e) acc += er[e] * W_ih[e * HD + c];
  ex[bt * HD + c] = acc;
}

// ---------------- prep 2: Wbt[n][k] = bf16(W_out[k][n]) ----------------
__global__ void prep_wt_kernel(const float* __restrict__ W_out, unsigned short* __restrict__ Wbt){
  __shared__ float tile[32][33];
  int tx = threadIdx.x & 31, ty = threadIdx.x >> 5;
  int n0 = blockIdx.x * 32, k0 = blockIdx.y * 32;
  #pragma unroll
  for (int j = 0; j < 4; ++j){
    int k = ty + j * 8;
    tile[k][tx] = W_out[(long)(k0 + k) * VOCAB + n0 + tx];
  }
  __syncthreads();
  #pragma unroll
  for (int j = 0; j < 4; ++j){
    int n = ty + j * 8;
    Wbt[(long)(n0 + n) * HD + k0 + tx] = f2bf(tile[tx][n]);
  }
}

// ---------------- scan: one workgroup per batch element, 3 barriers/step ----------------
// keysB[s] holds G = e^{2 k_s} (fp16); hWcB[s] holds h_s @ Wc (fp16). Rows 272B.
// All row reads guarded by s < t -> no zero-init needed.
__launch_bounds__(1024)
__global__ void scan_kernel(const float* __restrict__ W_attn, const float* __restrict__ U_attn,
                            const float* __restrict__ v_attn, const float* __restrict__ W_ih,
                            const float* __restrict__ W_hh, const float* __restrict__ ex,
                            unsigned short* __restrict__ out_bf, float* __restrict__ h_final){
  extern __shared__ char lds[];
  char* keysB = lds;                       // 256*272 = 69632 B
  char* hWcB  = lds + 69632;               // 69632 B
  float* fbuf   = (float*)(lds + 139264);
  float* E_pad    = fbuf;                  // 160 f32 (pad 4 per 16): e^{2q}
  float* hh_lds   = fbuf + 160;            // 128
  float* scores_e = fbuf + 288;            // 256
  float* pp       = fbuf + 544;            // 16
  unsigned* h_pk  = (unsigned*)(fbuf + 560); // 64 u32: h packed fp16 pairs

  const int b    = blockIdx.x;
  const int tid  = threadIdx.x;
  const int lane = tid & 63, wv = tid >> 6;
  const int c_   = tid >> 3, rg = tid & 7;      // phase-1 mapping
  const int sg   = lane >> 3, cg = lane & 7;    // phase-2 mapping
  const int cg3  = cg & 3;
  const int sgx  = sg + 8*(cg >> 2);            // phase-3: 0..15 s-stripe
  const int cp   = wv*4 + cg3;                  // phase-3: col pair -> cols 2cp,2cp+1

  const float LOG2E = 1.4426950408889634f;
  const float C2F   = 2.8853900817779268f;

  if (tid < HD) hh_lds[tid] = 0.f;
  if (tid < 64) h_pk[tid] = 0u;

  // ---- stage weights into packed-fp16 VGPRs ----
  unsigned Wa2[8], Ua2[8], Wh2[8], Wc2[8];
  {
    float* stage = (float*)lds;        // reuse keysB area
    float4* d4 = (float4*)stage;
    {
      const float4* s4 = (const float4*)W_attn;
      for (int i = 0; i < 4; ++i) d4[tid + i*1024] = s4[tid + i*1024];
      __syncthreads();
      #pragma unroll
      for (int i = 0; i < 8; ++i)
        Wa2[i] = pk2(stage[(rg*16 + 2*i)*HD + c_], stage[(rg*16 + 2*i + 1)*HD + c_]);
      __syncthreads();
    }
    {
      const float4* s4 = (const float4*)U_attn;
      for (int i = 0; i < 4; ++i) d4[tid + i*1024] = s4[tid + i*1024];
      __syncthreads();
      #pragma unroll
      for (int i = 0; i < 8; ++i)
        Ua2[i] = pk2(stage[(rg*16 + 2*i)*HD + c_], stage[(rg*16 + 2*i + 1)*HD + c_]);
      __syncthreads();
    }
    {
      const float4* s4 = (const float4*)W_hh;
      for (int i = 0; i < 4; ++i) d4[tid + i*1024] = s4[tid + i*1024];
      __syncthreads();
      #pragma unroll
      for (int i = 0; i < 8; ++i)
        Wh2[i] = pk2(stage[(rg*16 + 2*i)*HD + c_], stage[(rg*16 + 2*i + 1)*HD + c_]);
      __syncthreads();
    }
    {
      const float4* s4 = (const float4*)(W_ih + EMBD*HD);
      for (int i = 0; i < 4; ++i) d4[tid + i*1024] = s4[tid + i*1024];
      __syncthreads();
      #pragma unroll
      for (int i = 0; i < 8; ++i)
        Wc2[i] = pk2(stage[(rg*16 + 2*i)*HD + c_], stage[(rg*16 + 2*i + 1)*HD + c_]);
      __syncthreads();
    }
  }

  // ---- v in registers (cols cg*16..+15) + FULL 128-sum (butterfly), pre-scaled ----
  float vreg[16], VsumL;
  {
    const float* vg = v_attn + cg*16;
    float s = 0.f;
    #pragma unroll
    for (int i = 0; i < 16; ++i){ vreg[i] = vg[i]; s += vreg[i]; }
    s = dpp_add1(s); s = dpp_add2(s); s = swz_add4(s);   // butterfly: all lanes
    VsumL = s * LOG2E;
  }

  const float* exb = ex + (long)b * TLEN * HD;

  for (int t = 0; t < TLEN; ++t){
    float2 evpre = *(const float2*)(exb + t*HD + 2*cp);   // prefetch for P3 tail

    if (t > 0){
      // ---- P1: 4 packed GEMVs of h: q(->E=e^{2q}), k(->G=e^{2k}), hh, hWc ----
      {
        unsigned h2u[8];
        ld8u((const char*)h_pk + rg*32, h2u);
        float aq = 0.f, ak = 0.f, ah = 0.f, aw = 0.f;
        #pragma unroll
        for (int i = 0; i < 8; ++i){
          aq = fdot2u(h2u[i], Wa2[i], aq);
          ak = fdot2u(h2u[i], Ua2[i], ak);
          ah = fdot2u(h2u[i], Wh2[i], ah);
          aw = fdot2u(h2u[i], Wc2[i], aw);
        }
        aq = dpp_add1(aq); aq = dpp_add2(aq); aq = dpp_shl4(aq);
        ak = dpp_add1(ak); ak = dpp_add2(ak); ak = dpp_shl4(ak);
        ah = dpp_add1(ah); ah = dpp_add2(ah); ah = dpp_shl4(ah);
        aw = dpp_add1(aw); aw = dpp_add2(aw); aw = dpp_shl4(aw);
        if (rg == 0){
          E_pad[c_ + (c_>>4)*4] = __builtin_amdgcn_exp2f(aq * C2F);      // e^{2q}
          hh_lds[c_] = ah;
          int s = t - 1;
          float G = fminf(__builtin_amdgcn_exp2f(ak * C2F), 60000.f);    // e^{2k}
          *(unsigned short*)(keysB + s*ROWB + c_*2) = f2h(G);
          *(unsigned short*)(hWcB  + s*ROWB + c_*2) = f2h(aw);
        }
      }
      __syncthreads();  // S1

      // ---- P2: e_s = exp(v . tanh(q+k_s));  tanh = 1 - 2/(1 + E*G), quad-rcp ----
      {
        float Ereg[16];
        {
          const float4* E4 = (const float4*)(E_pad + cg*20);
          #pragma unroll
          for (int i = 0; i < 4; ++i){
            float4 ev = E4[i];
            Ereg[i*4+0]=ev.x; Ereg[i*4+1]=ev.y; Ereg[i*4+2]=ev.z; Ereg[i*4+3]=ev.w;
          }
        }
        float e1 = 0.f, e2 = 0.f;
        #pragma unroll
        for (int it = 0; it < 2; ++it){
          int s = wv*8 + sg + it*128;
          if (s < t){
            const char* kb = keysB + s*ROWB + cg*32;
            ushort8v g0 = *(const ushort8v*)kb;
            ushort8v g1 = *(const ushort8v*)(kb + 16);
            float ac = 0.f;
            #pragma unroll
            for (int jj = 0; jj < 4; ++jj){
              float D0 = fmaf(Ereg[2*jj],     h2f(g0[2*jj]),   1.f);
              float D1 = fmaf(Ereg[2*jj+1],   h2f(g0[2*jj+1]), 1.f);
              float D2 = fmaf(Ereg[8+2*jj],   h2f(g1[2*jj]),   1.f);
              float D3 = fmaf(Ereg[8+2*jj+1], h2f(g1[2*jj+1]), 1.f);
              float P01 = D0*D1, P23 = D2*D3;
              float R   = __builtin_amdgcn_rcpf(P01*P23);
              float R01 = R*P23, R23 = R*P01;
              ac = fmaf(vreg[2*jj],     R01*D1, ac);
              ac = fmaf(vreg[2*jj+1],   R01*D0, ac);
              ac = fmaf(vreg[8+2*jj],   R23*D3, ac);
              ac = fmaf(vreg[8+2*jj+1], R23*D2, ac);
            }
            ac = dpp_add1(ac); ac = dpp_add2(ac); ac = dpp_shl4(ac);   // cg-reduce
            float e = __builtin_amdgcn_exp2f(fmaf(-C2F, ac, VsumL));
            if (cg == 0) scores_e[s] = e;
            if (it == 0) e1 = e; else e2 = e;
          }
        }
        float esum = e1 + e2;                              // valid at cg==0 lanes
        esum = dpp_shl8(esum); esum = swz_add16(esum); esum += __shfl_xor(esum, 32);
        if (lane == 0) pp[wv] = esum;
      }
      __syncthreads();  // S2
    }

    // ---- P3: ctxWc[col] = (sum_s e_s * hWc[s][col]) / Z, then h_new inline ----
    {
      float4 p0 = ((const float4*)pp)[0], p1v = ((const float4*)pp)[1];
      float4 p2v = ((const float4*)pp)[2], p3 = ((const float4*)pp)[3];
      float sum = (p0.x+p0.y+p0.z+p0.w) + (p1v.x+p1v.y+p1v.z+p1v.w)
                + (p2v.x+p2v.y+p2v.z+p2v.w) + (p3.x+p3.y+p3.z+p3.w);
      float invZ = __builtin_amdgcn_rcpf(sum);         // garbage at t=0, selected away
      float a0 = 0.f, a1 = 0.f;
      const char* p = hWcB + cp*4 + sgx*ROWB;
      int s = sgx;
      for (; s + 16 < t; s += 32){
        float  e0  = scores_e[s];
        unsigned hv0 = *(const unsigned*)p;
        float  eS  = scores_e[s+16];
        unsigned hv1 = *(const unsigned*)(p + 16*ROWB);
        float2 f0 = __half22float2(__builtin_bit_cast(__half2, hv0));
        float2 f1 = __half22float2(__builtin_bit_cast(__half2, hv1));
        a0 = fmaf(e0, f0.x, a0); a1 = fmaf(e0, f0.y, a1);
        a0 = fmaf(eS, f1.x, a0); a1 = fmaf(eS, f1.y, a1);
        p += 32*ROWB;
      }
      if (s < t){
        float e0 = scores_e[s];
        unsigned hv0 = *(const unsigned*)p;
        float2 f0 = __half22float2(__builtin_bit_cast(__half2, hv0));
        a0 = fmaf(e0, f0.x, a0); a1 = fmaf(e0, f0.y, a1);
      }
      a0 = dpp_shl4(a0); a0 = dpp_shl8(a0); a0 = swz_add16(a0); a0 += __shfl_xor(a0, 32);
      a1 = dpp_shl4(a1); a1 = dpp_shl8(a1); a1 = swz_add16(a1); a1 += __shfl_xor(a1, 32);
      if (sgx == 0){
        float cw0 = (t > 0) ? a0 * invZ : 0.f;
        float cw1 = (t > 0) ? a1 * invZ : 0.f;
        int c0 = 2*cp;
        float2 hhv = *(const float2*)(&hh_lds[c0]);
        float h0 = tanhfast(evpre.x + hhv.x + cw0);
        float h1 = tanhfast(evpre.y + hhv.y + cw1);
        h_pk[cp] = pk2(h0, h1);
        unsigned po = (unsigned)f2bf(h0) | ((unsigned)f2bf(h1) << 16);
        *(unsigned*)(&out_bf[((long)b*TLEN + t)*HD + c0]) = po;
        if (t == TLEN-1){ float2 hw = { h0, h1 }; *(float2*)&h_final[b*HD + c0] = hw; }
      }
    }
    __syncthreads();  // S3: h visible for next step's P1
  }
}

// ---------------- logits GEMM: [2048,128]bf16 @ Wbt[32000,128]^T + bias ----------------
__launch_bounds__(256, 2)
__global__ void gemm_kernel(const unsigned short* __restrict__ A, const unsigned short* __restrict__ Bt,
                            const float* __restrict__ bias, float* __restrict__ C){
  __shared__ char sAB[65536];
  char* sA = sAB;
  char* sB = sAB + 32768;
  const int tid = threadIdx.x;
  const int lane = tid & 63, wv = tid >> 6;
  const int n0 = blockIdx.x * 128, m0 = blockIdx.y * 128;
  const char* Ab = (const char*)A + (long)m0 * 256;
  const char* Bb = (const char*)Bt + (long)n0 * 256;

  #pragma unroll
  for (int it = 0; it < 8; ++it){
    int p  = it*4096 + wv*1024 + lane*16;
    int ps = p ^ (((p >> 8) & 7) << 4);
    gload_lds16(Ab + ps, sA + it*4096 + wv*1024);
    gload_lds16(Bb + ps, sB + it*4096 + wv*1024);
  }
  __syncthreads();

  f32x4 acc[2][8] = {};
  const int r15 = lane & 15, r4 = lane >> 4;
  #pragma unroll
  for (int kk = 0; kk < 4; ++kk){
    short8v af[2], bfr[8];
    #pragma unroll
    for (int mi = 0; mi < 2; ++mi){
      int row = wv*32 + mi*16 + r15;
      int off = row*256 + kk*64 + r4*16;
      af[mi] = *(const short8v*)(sA + (off ^ ((row & 7) << 4)));
    }
    #pragma unroll
    for (int ni = 0; ni < 8; ++ni){
      int row = ni*16 + r15;
      int off = row*256 + kk*64 + r4*16;
      bfr[ni] = *(const short8v*)(sB + (off ^ ((row & 7) << 4)));
    }
    #pragma unroll
    for (int ni = 0; ni < 8; ++ni)
      #pragma unroll
      for (int mi = 0; mi < 2; ++mi)
        acc[mi][ni] = __builtin_amdgcn_mfma_f32_16x16x32_bf16(af[mi], bfr[ni], acc[mi][ni], 0, 0, 0);
  }

  #pragma unroll
  for (int mi = 0; mi < 2; ++mi){
    int rbase = m0 + wv*32 + mi*16 + r4*4;
    #pragma unroll
    for (int ni = 0; ni < 8; ++ni){
      int col = n0 + ni*16 + r15;
      float bv = bias[col];
      #pragma unroll
      for (int j = 0; j < 4; ++j)
        C[(long)(rbase + j) * VOCAB + col] = acc[mi][ni][j] + bv;
    }
  }
}

extern "C" void kernel_launch(void* const* d_in, const int* in_sizes, int n_in,
                              void* d_out, int out_size, void* d_ws, size_t ws_size,
                              hipStream_t stream){
  const int*   x      = (const int*)d_in[0];
  const float* emb    = (const float*)d_in[1];
  const float* W_attn = (const float*)d_in[2];
  const float* U_attn = (const float*)d_in[3];
  const float* v_attn = (const float*)d_in[4];
  const float* W_ih   = (const float*)d_in[5];
  const float* b_ih   = (const float*)d_in[6];
  const float* W_hh   = (const float*)d_in[7];
  const float* b_hh   = (const float*)d_in[8];
  const float* W_out  = (const float*)d_in[9];
  const float* b_out  = (const float*)d_in[10];

  float* logits  = (float*)d_out;
  float* h_final = logits + (long)BATCH * TLEN * VOCAB;

  char* ws = (char*)d_ws;
  float*          ex   = (float*)ws;                                // 1 MB
  unsigned short* Wbt  = (unsigned short*)(ws + 1048576);           // 8.192 MB
  unsigned short* outb = (unsigned short*)(ws + 1048576 + 8192000); // 0.5 MB

  prep_ex_kernel<<<BATCH*TLEN, HD, 0, stream>>>(x, emb, W_ih, b_ih, b_hh, ex);
  prep_wt_kernel<<<dim3(VOCAB/32, HD/32), 256, 0, stream>>>(W_out, Wbt);

  const int ldsBytes = 139264 + 624*4;   // 141,760 B
  hipFuncSetAttribute((const void*)scan_kernel, hipFuncAttributeMaxDynamicSharedMemorySize, ldsBytes);
  scan_kernel<<<BATCH, 1024, ldsBytes, stream>>>(W_attn, U_attn, v_attn, W_ih, W_hh, ex, outb, h_final);

  gemm_kernel<<<dim3(VOCAB/128, (BATCH*TLEN)/128), 256, 0, stream>>>(outb, Wbt, b_out, logits);
}

// Round 10
// 690.099 us; speedup vs baseline: 2.1916x; 1.0127x over previous
//
#include <hip/hip_runtime.h>
#include <hip/hip_fp16.h>
#include <hip/hip_bf16.h>
#include <cstdint>

#define TLEN  256
#define HD    128
#define BATCH 8
#define VOCAB 32000
#define EMBD  32
#define ROWB  272   // 256B row + 16B pad

typedef __attribute__((ext_vector_type(8))) short short8v;
typedef __attribute__((ext_vector_type(8))) unsigned short ushort8v;
typedef __attribute__((ext_vector_type(4))) float f32x4;
typedef __attribute__((ext_vector_type(2))) float f32x2;
typedef __attribute__((ext_vector_type(2))) _Float16 hv2;

__device__ __forceinline__ float tanhfast(float x){
  float e = __builtin_amdgcn_exp2f(x * 2.8853900817779268f);
  return 1.0f - 2.0f * __builtin_amdgcn_rcpf(e + 1.0f);
}
__device__ __forceinline__ unsigned short f2bf(float f){
  unsigned u = __float_as_uint(f);
  return (unsigned short)((u + 0x7fffu + ((u >> 16) & 1u)) >> 16);
}
__device__ __forceinline__ float h2f(unsigned short u){
  return __half2float(__ushort_as_half(u));
}
__device__ __forceinline__ unsigned short f2h(float f){
  return __half_as_ushort(__float2half(f));
}
__device__ __forceinline__ unsigned pk2(float lo, float hi){
  return __builtin_bit_cast(unsigned, __floats2half2_rn(lo, hi));
}
__device__ __forceinline__ float fdot2u(unsigned a, unsigned b, float c){
#if __has_builtin(__builtin_amdgcn_fdot2)
  return __builtin_amdgcn_fdot2(__builtin_bit_cast(hv2, a), __builtin_bit_cast(hv2, b), c, false);
#else
  float2 fa = __half22float2(__builtin_bit_cast(__half2, a));
  float2 fb = __half22float2(__builtin_bit_cast(__half2, b));
  return c + fa.x*fb.x + fa.y*fb.y;
#endif
}
__device__ __forceinline__ f32x2 fma2(f32x2 a, f32x2 b, f32x2 c){
#if __has_builtin(__builtin_elementwise_fma)
  return __builtin_elementwise_fma(a, b, c);
#else
  f32x2 r; r.x = fmaf(a.x, b.x, c.x); r.y = fmaf(a.y, b.y, c.y); return r;
#endif
}
__device__ __forceinline__ f32x2 cvt2(unsigned w){
  f32x2 r; r.x = h2f((unsigned short)(w & 0xFFFFu)); r.y = h2f((unsigned short)(w >> 16)); return r;
}
__device__ __forceinline__ void ld8u(const void* p, unsigned* d){
  uint4 a = *(const uint4*)p;
  uint4 b = *(const uint4*)((const char*)p + 16);
  d[0]=a.x; d[1]=a.y; d[2]=a.z; d[3]=a.w; d[4]=b.x; d[5]=b.y; d[6]=b.z; d[7]=b.w;
}
__device__ __forceinline__ void gload_lds16(const void* g, void* l){
  __builtin_amdgcn_global_load_lds((const __attribute__((address_space(1))) void*)g,
                                   (__attribute__((address_space(3))) void*)l, 16, 0, 0);
}

// ---- cross-lane adds ----
__device__ __forceinline__ float dpp_add1(float x){   // + lane^1
  int y = __builtin_amdgcn_mov_dpp(__float_as_int(x), 0xB1, 0xF, 0xF, true);
  return x + __int_as_float(y);
}
__device__ __forceinline__ float dpp_add2(float x){   // + lane^2
  int y = __builtin_amdgcn_mov_dpp(__float_as_int(x), 0x4E, 0xF, 0xF, true);
  return x + __int_as_float(y);
}
__device__ __forceinline__ float dpp_shl4(float x){   // + lane+4 (valid (l&15)<12)
  int y = __builtin_amdgcn_mov_dpp(__float_as_int(x), 0x104, 0xF, 0xF, true);
  return x + __int_as_float(y);
}
__device__ __forceinline__ float dpp_shl8(float x){   // + lane+8 (valid (l&15)<8)
  int y = __builtin_amdgcn_mov_dpp(__float_as_int(x), 0x108, 0xF, 0xF, true);
  return x + __int_as_float(y);
}
__device__ __forceinline__ float swz_add4(float x){   // + lane^4
  int y = __builtin_amdgcn_ds_swizzle(__float_as_int(x), 0x101F);
  return x + __int_as_float(y);
}
__device__ __forceinline__ float swz_add16(float x){  // + lane^16
  int y = __builtin_amdgcn_ds_swizzle(__float_as_int(x), 0x401F);
  return x + __int_as_float(y);
}

// interleaved score slot: stripe-contiguous for P3
#define SCR(s) ((((s) & 15) << 4) | ((s) >> 4))

// ---------------- prep 1 ----------------
__global__ void prep_ex_kernel(const int* __restrict__ x, const float* __restrict__ emb,
                               const float* __restrict__ W_ih, const float* __restrict__ b_ih,
                               const float* __restrict__ b_hh, float* __restrict__ ex){
  int bt = blockIdx.x;
  int c  = threadIdx.x;
  int ix = x[bt];
  const float* er = emb + (long)ix * EMBD;
  float acc = b_ih[c] + b_hh[c];
  #pragma unroll
  for (int e = 0; e < EMBD; ++e) acc += er[e] * W_ih[e * HD + c];
  ex[bt * HD + c] = acc;
}

// ---------------- prep 2 ----------------
__global__ void prep_wt_kernel(const float* __restrict__ W_out, unsigned short* __restrict__ Wbt){
  __shared__ float tile[32][33];
  int tx = threadIdx.x & 31, ty = threadIdx.x >> 5;
  int n0 = blockIdx.x * 32, k0 = blockIdx.y * 32;
  #pragma unroll
  for (int j = 0; j < 4; ++j){
    int k = ty + j * 8;
    tile[k][tx] = W_out[(long)(k0 + k) * VOCAB + n0 + tx];
  }
  __syncthreads();
  #pragma unroll
  for (int j = 0; j < 4; ++j){
    int n = ty + j * 8;
    Wbt[(long)(n0 + n) * HD + k0 + tx] = f2bf(tile[tx][n]);
  }
}

// ---------------- scan ----------------
__launch_bounds__(1024)
__global__ void scan_kernel(const float* __restrict__ W_attn, const float* __restrict__ U_attn,
                            const float* __restrict__ v_attn, const float* __restrict__ W_ih,
                            const float* __restrict__ W_hh, const float* __restrict__ ex,
                            unsigned short* __restrict__ out_bf, float* __restrict__ h_final){
  extern __shared__ char lds[];
  char* keysB = lds;                       // 256*272 = 69632 B (G = e^{2k}, fp16)
  char* hWcB  = lds + 69632;               // 69632 B (h@Wc, fp16) -- zero-backed
  float* fbuf   = (float*)(lds + 139264);
  float* E_pad    = fbuf;                  // 160: e^{2q}
  float* hh_lds   = fbuf + 160;            // 128
  float* scores_e = fbuf + 288;            // 256 (interleaved SCR layout, zero-backed)
  float* pp       = fbuf + 544;            // 16
  unsigned* h_pk  = (unsigned*)(fbuf + 560); // 64

  const int b    = blockIdx.x;
  const int tid  = threadIdx.x;
  const int lane = tid & 63, wv = tid >> 6;
  const int c_   = tid >> 3, rg = tid & 7;
  const int sg   = lane >> 3, cg = lane & 7;
  const int cg3  = cg & 3;
  const int sgx  = sg + 8*(cg >> 2);            // 0..15
  const int cp   = wv*4 + cg3;                  // col pair -> cols 2cp,2cp+1

  const float LOG2E = 1.4426950408889634f;
  const float C2F   = 2.8853900817779268f;

  if (tid < HD) hh_lds[tid] = 0.f;

  // ---- stage weights into packed-fp16 VGPRs ----
  unsigned Wa2[8], Ua2[8], Wh2[8], Wc2[8];
  {
    float* stage = (float*)lds;
    float4* d4 = (float4*)stage;
    {
      const float4* s4 = (const float4*)W_attn;
      for (int i = 0; i < 4; ++i) d4[tid + i*1024] = s4[tid + i*1024];
      __syncthreads();
      #pragma unroll
      for (int i = 0; i < 8; ++i)
        Wa2[i] = pk2(stage[(rg*16 + 2*i)*HD + c_], stage[(rg*16 + 2*i + 1)*HD + c_]);
      __syncthreads();
    }
    {
      const float4* s4 = (const float4*)U_attn;
      for (int i = 0; i < 4; ++i) d4[tid + i*1024] = s4[tid + i*1024];
      __syncthreads();
      #pragma unroll
      for (int i = 0; i < 8; ++i)
        Ua2[i] = pk2(stage[(rg*16 + 2*i)*HD + c_], stage[(rg*16 + 2*i + 1)*HD + c_]);
      __syncthreads();
    }
    {
      const float4* s4 = (const float4*)W_hh;
      for (int i = 0; i < 4; ++i) d4[tid + i*1024] = s4[tid + i*1024];
      __syncthreads();
      #pragma unroll
      for (int i = 0; i < 8; ++i)
        Wh2[i] = pk2(stage[(rg*16 + 2*i)*HD + c_], stage[(rg*16 + 2*i + 1)*HD + c_]);
      __syncthreads();
    }
    {
      const float4* s4 = (const float4*)(W_ih + EMBD*HD);
      for (int i = 0; i < 4; ++i) d4[tid + i*1024] = s4[tid + i*1024];
      __syncthreads();
      #pragma unroll
      for (int i = 0; i < 8; ++i)
        Wc2[i] = pk2(stage[(rg*16 + 2*i)*HD + c_], stage[(rg*16 + 2*i + 1)*HD + c_]);
      __syncthreads();
    }
  }

  // ---- zero-back hWcB (4352 f4) + scores_e (64 f4): unwritten rows read as 0 ----
  {
    float4 z = {0.f, 0.f, 0.f, 0.f};
    float4* hz = (float4*)hWcB;
    hz[tid] = z; hz[tid + 1024] = z; hz[tid + 2048] = z; hz[tid + 3072] = z;
    if (tid < 256) hz[tid + 4096] = z;
    if (tid < 64) ((float4*)scores_e)[tid] = z;
    if (tid < 64) h_pk[tid] = 0u;
  }
  // (visible before first use at t=1 via the in-loop barriers)

  // ---- v in registers (cols cg*16..+15) as f32x2 + FULL 128-sum ----
  f32x2 v2[8]; float VsumL;
  {
    const float* vg = v_attn + cg*16;
    float s = 0.f;
    #pragma unroll
    for (int i = 0; i < 8; ++i){
      f32x2 vv; vv.x = vg[2*i]; vv.y = vg[2*i+1];
      v2[i] = vv; s += vv.x + vv.y;
    }
    s = dpp_add1(s); s = dpp_add2(s); s = swz_add4(s);
    VsumL = s * LOG2E;
  }

  const float* exb = ex + (long)b * TLEN * HD;

  for (int t = 0; t < TLEN; ++t){
    float2 evpre = *(const float2*)(exb + t*HD + 2*cp);   // prefetch for P3 tail

    if (t > 0){
      // ---- P1: 4 packed GEMVs of h ----
      {
        unsigned h2u[8];
        ld8u((const char*)h_pk + rg*32, h2u);
        float aq = 0.f, ak = 0.f, ah = 0.f, aw = 0.f;
        #pragma unroll
        for (int i = 0; i < 8; ++i){
          aq = fdot2u(h2u[i], Wa2[i], aq);
          ak = fdot2u(h2u[i], Ua2[i], ak);
          ah = fdot2u(h2u[i], Wh2[i], ah);
          aw = fdot2u(h2u[i], Wc2[i], aw);
        }
        aq = dpp_add1(aq); aq = dpp_add2(aq); aq = dpp_shl4(aq);
        ak = dpp_add1(ak); ak = dpp_add2(ak); ak = dpp_shl4(ak);
        ah = dpp_add1(ah); ah = dpp_add2(ah); ah = dpp_shl4(ah);
        aw = dpp_add1(aw); aw = dpp_add2(aw); aw = dpp_shl4(aw);
        if (rg == 0){
          E_pad[c_ + (c_>>4)*4] = __builtin_amdgcn_exp2f(aq * C2F);      // e^{2q}
          hh_lds[c_] = ah;
          int s = t - 1;
          float G = fminf(__builtin_amdgcn_exp2f(ak * C2F), 60000.f);    // e^{2k}
          *(unsigned short*)(keysB + s*ROWB + c_*2) = f2h(G);
          *(unsigned short*)(hWcB  + s*ROWB + c_*2) = f2h(aw);
        }
      }
      __syncthreads();  // S1

      // ---- P2: e_s = exp(v . tanh(q+k_s)); tanh = 1 - 2/(1+E*G); packed f32 ----
      {
        f32x2 E2[8];
        {
          const float4* E4 = (const float4*)(E_pad + cg*20);
          #pragma unroll
          for (int i = 0; i < 4; ++i){
            float4 ev = E4[i];
            f32x2 a, bb; a.x = ev.x; a.y = ev.y; bb.x = ev.z; bb.y = ev.w;
            E2[2*i] = a; E2[2*i+1] = bb;
          }
        }
        float e1 = 0.f, e2 = 0.f;
        #pragma unroll
        for (int it = 0; it < 2; ++it){
          int s = wv*8 + sg + it*128;
          if (s < t){
            const char* kb = keysB + s*ROWB + cg*32;
            ushort8v g0 = *(const ushort8v*)kb;
            ushort8v g1 = *(const ushort8v*)(kb + 16);
            f32x2 D[8];
            #pragma unroll
            for (int i = 0; i < 4; ++i){
              f32x2 ga; ga.x = h2f(g0[2*i]); ga.y = h2f(g0[2*i+1]);
              f32x2 gb; gb.x = h2f(g1[2*i]); gb.y = h2f(g1[2*i+1]);
              f32x2 one; one.x = 1.f; one.y = 1.f;
              D[i]   = fma2(E2[i],   ga, one);
              D[4+i] = fma2(E2[4+i], gb, one);
            }
            f32x2 acc2; acc2.x = 0.f; acc2.y = 0.f;
            #pragma unroll
            for (int i = 0; i < 8; i += 2){
              f32x2 p = D[i] * D[i+1];
              float R = __builtin_amdgcn_rcpf(p.x * p.y);
              f32x2 sw = p.yx * R;
              acc2 = fma2(v2[i],   sw * D[i+1], acc2);
              acc2 = fma2(v2[i+1], sw * D[i],   acc2);
            }
            float ac = acc2.x + acc2.y;
            ac = dpp_add1(ac); ac = dpp_add2(ac); ac = dpp_shl4(ac);   // cg-reduce
            float e = __builtin_amdgcn_exp2f(fmaf(-C2F, ac, VsumL));
            if (cg == 0) scores_e[SCR(s)] = e;
            if (it == 0) e1 = e; else e2 = e;
          }
        }
        float esum = e1 + e2;                              // valid at cg==0 lanes
        esum = dpp_shl8(esum); esum = swz_add16(esum); esum += __shfl_xor(esum, 32);
        if (lane == 0) pp[wv] = esum;
      }
      __syncthreads();  // S2
    }

    // ---- P3: ctxWc = (sum_s e_s * hWc[s]) / Z, then h_new inline ----
    {
      float4 p0 = ((const float4*)pp)[0], p1v = ((const float4*)pp)[1];
      float4 p2v = ((const float4*)pp)[2], p3 = ((const float4*)pp)[3];
      float sum = (p0.x+p0.y+p0.z+p0.w) + (p1v.x+p1v.y+p1v.z+p1v.w)
                + (p2v.x+p2v.y+p2v.z+p2v.w) + (p3.x+p3.y+p3.z+p3.w);
      float invZ = __builtin_amdgcn_rcpf(sum);         // garbage at t=0, selected away
      f32x2 a2; a2.x = 0.f; a2.y = 0.f;
      const char* pw = hWcB + cp*4 + sgx*ROWB;
      const float* sc = scores_e + sgx*16;
      int jmax = (t - sgx + 15) >> 4;                  // #valid stripe slots (<=16)
      for (int j = 0; j < jmax; j += 4){
        float4 e4 = *(const float4*)(sc + j);          // 4 scores, zero-backed
        unsigned w0 = *(const unsigned*)(pw);
        unsigned w1 = *(const unsigned*)(pw + 16*ROWB);
        unsigned w2 = *(const unsigned*)(pw + 32*ROWB);
        unsigned w3 = *(const unsigned*)(pw + 48*ROWB);
        f32x2 s0; s0.x = e4.x; s0.y = e4.x;
        f32x2 s1; s1.x = e4.y; s1.y = e4.y;
        f32x2 s2; s2.x = e4.z; s2.y = e4.z;
        f32x2 s3; s3.x = e4.w; s3.y = e4.w;
        a2 = fma2(s0, cvt2(w0), a2);
        a2 = fma2(s1, cvt2(w1), a2);
        a2 = fma2(s2, cvt2(w2), a2);
        a2 = fma2(s3, cvt2(w3), a2);
        pw += 64*ROWB;
      }
      float a0 = a2.x, a1 = a2.y;
      a0 = dpp_shl4(a0); a0 = dpp_shl8(a0); a0 = swz_add16(a0); a0 += __shfl_xor(a0, 32);
      a1 = dpp_shl4(a1); a1 = dpp_shl8(a1); a1 = swz_add16(a1); a1 += __shfl_xor(a1, 32);
      if (sgx == 0){
        float cw0 = (t > 0) ? a0 * invZ : 0.f;
        float cw1 = (t > 0) ? a1 * invZ : 0.f;
        int c0 = 2*cp;
        float2 hhv = *(const float2*)(&hh_lds[c0]);
        float h0 = tanhfast(evpre.x + hhv.x + cw0);
        float h1 = tanhfast(evpre.y + hhv.y + cw1);
        h_pk[cp] = pk2(h0, h1);
        unsigned po = (unsigned)f2bf(h0) | ((unsigned)f2bf(h1) << 16);
        *(unsigned*)(&out_bf[((long)b*TLEN + t)*HD + c0]) = po;
        if (t == TLEN-1){ float2 hw = { h0, h1 }; *(float2*)&h_final[b*HD + c0] = hw; }
      }
    }
    __syncthreads();  // S3
  }
}

// ---------------- logits GEMM ----------------
__launch_bounds__(256, 2)
__global__ void gemm_kernel(const unsigned short* __restrict__ A, const unsigned short* __restrict__ Bt,
                            const float* __restrict__ bias, float* __restrict__ C){
  __shared__ char sAB[65536];
  char* sA = sAB;
  char* sB = sAB + 32768;
  const int tid = threadIdx.x;
  const int lane = tid & 63, wv = tid >> 6;
  const int n0 = blockIdx.x * 128, m0 = blockIdx.y * 128;
  const char* Ab = (const char*)A + (long)m0 * 256;
  const char* Bb = (const char*)Bt + (long)n0 * 256;

  #pragma unroll
  for (int it = 0; it < 8; ++it){
    int p  = it*4096 + wv*1024 + lane*16;
    int ps = p ^ (((p >> 8) & 7) << 4);
    gload_lds16(Ab + ps, sA + it*4096 + wv*1024);
    gload_lds16(Bb + ps, sB + it*4096 + wv*1024);
  }
  __syncthreads();

  f32x4 acc[2][8] = {};
  const int r15 = lane & 15, r4 = lane >> 4;
  #pragma unroll
  for (int kk = 0; kk < 4; ++kk){
    short8v af[2], bfr[8];
    #pragma unroll
    for (int mi = 0; mi < 2; ++mi){
      int row = wv*32 + mi*16 + r15;
      int off = row*256 + kk*64 + r4*16;
      af[mi] = *(const short8v*)(sA + (off ^ ((row & 7) << 4)));
    }
    #pragma unroll
    for (int ni = 0; ni < 8; ++ni){
      int row = ni*16 + r15;
      int off = row*256 + kk*64 + r4*16;
      bfr[ni] = *(const short8v*)(sB + (off ^ ((row & 7) << 4)));
    }
    #pragma unroll
    for (int ni = 0; ni < 8; ++ni)
      #pragma unroll
      for (int mi = 0; mi < 2; ++mi)
        acc[mi][ni] = __builtin_amdgcn_mfma_f32_16x16x32_bf16(af[mi], bfr[ni], acc[mi][ni], 0, 0, 0);
  }

  #pragma unroll
  for (int mi = 0; mi < 2; ++mi){
    int rbase = m0 + wv*32 + mi*16 + r4*4;
    #pragma unroll
    for (int ni = 0; ni < 8; ++ni){
      int col = n0 + ni*16 + r15;
      float bv = bias[col];
      #pragma unroll
      for (int j = 0; j < 4; ++j)
        C[(long)(rbase + j) * VOCAB + col] = acc[mi][ni][j] + bv;
    }
  }
}

extern "C" void kernel_launch(void* const* d_in, const int* in_sizes, int n_in,
                              void* d_out, int out_size, void* d_ws, size_t ws_size,
                              hipStream_t stream){
  const int*   x      = (const int*)d_in[0];
  const float* emb    = (const float*)d_in[1];
  const float* W_attn = (const float*)d_in[2];
  const float* U_attn = (const float*)d_in[3];
  const float* v_attn = (const float*)d_in[4];
  const float* W_ih   = (const float*)d_in[5];
  const float* b_ih   = (const float*)d_in[6];
  const float* W_hh   = (const float*)d_in[7];
  const float* b_hh   = (const float*)d_in[8];
  const float* W_out  = (const float*)d_in[9];
  const float* b_out  = (const float*)d_in[10];

  float* logits  = (float*)d_out;
  float* h_final = logits + (long)BATCH * TLEN * VOCAB;

  char* ws = (char*)d_ws;
  float*          ex   = (float*)ws;                                // 1 MB
  unsigned short* Wbt  = (unsigned short*)(ws + 1048576);           // 8.192 MB
  unsigned short* outb = (unsigned short*)(ws + 1048576 + 8192000); // 0.5 MB

  prep_ex_kernel<<<BATCH*TLEN, HD, 0, stream>>>(x, emb, W_ih, b_ih, b_hh, ex);
  prep_wt_kernel<<<dim3(VOCAB/32, HD/32), 256, 0, stream>>>(W_out, Wbt);

  const int ldsBytes = 139264 + 624*4;   // 141,760 B
  hipFuncSetAttribute((const void*)scan_kernel, hipFuncAttributeMaxDynamicSharedMemorySize, ldsBytes);
  scan_kernel<<<BATCH, 1024, ldsBytes, stream>>>(W_attn, U_attn, v_attn, W_ih, W_hh, ex, outb, h_final);

  gemm_kernel<<<dim3(VOCAB/128, (BATCH*TLEN)/128), 256, 0, stream>>>(outb, Wbt, b_out, logits);
}